// Round 12
// baseline (119.083 us; speedup 1.0000x reference)
//
#include <hip/hip_runtime.h>
#include <math.h>

#define BB 4
#define HH 64
#define WW 64
#define CC 64
#define NN (HH*WW)          // 4096 pixels per batch
#define NPIX (BB*NN)        // 16384 total pixels
#define EPS 1e-3f
#define QBLK 32
#define KSPLIT 16
#define NQT32 (NPIX/QBLK)   // 512 query tiles of 32
#define NCHK ((NN/KSPLIT)/64)  // 4 chunks of 64 keys per segment

using bf16x8 = __attribute__((ext_vector_type(8))) short;
using f32x4  = __attribute__((ext_vector_type(4))) float;
using f32x16 = __attribute__((ext_vector_type(16))) float;

__device__ inline unsigned short bf16bits(float f) {
    union { float f; unsigned u; } a; a.f = f;
    unsigned r = a.u + 0x7fffu + ((a.u >> 16) & 1u);   // RNE
    return (unsigned short)(r >> 16);
}
__device__ inline unsigned packbf(float lo, float hi) {
    return (unsigned)bf16bits(lo) | ((unsigned)bf16bits(hi) << 16);
}
__device__ inline unsigned cvtpk(float lo, float hi) {
    unsigned r;
    asm("v_cvt_pk_bf16_f32 %0, %1, %2" : "=v"(r) : "v"(lo), "v"(hi));
    return r;
}
#define PSWAP(a, b) asm("v_permlane32_swap_b32 %0, %1" : "+v"(a), "+v"(b))

// raw 2^x (no libm edge handling; inputs are bounded scores)
__device__ __forceinline__ float exp2g(float x) {
    float r;
    asm("v_exp_f32 %0, %1" : "=v"(r) : "v"(x));
    return r;
}

// Q pre-scale: (1/8) * log2(e) so attention softmax uses 2^x directly
#define QSCALE 0.18033688011112042f

// ---------------- Kernel 1: GN partials + weight prep + accum zeroing -----
// grid 532: [0,256) GN partials; [256,272) wt_prep; [272,532) zero oacc/sacc.
__global__ __launch_bounds__(256) void gn_wt(const float* __restrict__ x,
                                             float* __restrict__ part,
                                             const float* __restrict__ wq,
                                             const float* __restrict__ wk,
                                             const float* __restrict__ wv,
                                             const float* __restrict__ wo,
                                             short* __restrict__ wfrag,
                                             float* __restrict__ zbase) {
    int t = threadIdx.x;
    if (blockIdx.x < 256) {
        int c = t & 63, rr = t >> 6;
        int p0 = blockIdx.x * 64;
        float s = 0.f, s2 = 0.f;
        #pragma unroll
        for (int k = 0; k < 16; ++k) {
            float v = x[(size_t)(p0 + rr + 4 * k) * CC + c];
            s += v; s2 += v * v;
        }
        __shared__ float sA[256], sB[256];
        sA[t] = s; sB[t] = s2;
        __syncthreads();
        if (t < 64) {
            float fs  = sA[t] + sA[64 + t] + sA[128 + t] + sA[192 + t];
            float fs2 = sB[t] + sB[64 + t] + sB[128 + t] + sB[192 + t];
            part[blockIdx.x * 128 + t]      = fs;
            part[blockIdx.x * 128 + 64 + t] = fs2;
        }
    } else if (blockIdx.x < 272) {
        const float* mats[3] = {wq, wk, wv};
        int i0 = (blockIdx.x - 256) * 256 + t;
        for (int e = i0; e < 12288; e += 16 * 256) {
            int m = e >> 12;
            int r = e & 4095;
            int dt = r >> 10, h = (r >> 9) & 1, lane = (r >> 3) & 63, j = r & 7;
            int g = lane >> 4, cl = lane & 15;
            float v = mats[m][(h * 32 + g * 8 + j) * 64 + dt * 16 + cl];
            wfrag[e] = (short)bf16bits(v);
        }
        for (int e = i0; e < 4096; e += 16 * 256) {
            int j = e & 7, lane = (e >> 3) & 63, dt = (e >> 9) & 1, s = e >> 10;
            int hi = lane >> 5, l31 = lane & 31;
            float v = wo[(8 * hi + 16 * s + j) * 64 + dt * 32 + l31];
            wfrag[12288 + e] = (short)bf16bits(v);
        }
    } else {
        // zero oaccum (NPIX*CC f32) + saccum (NPIX f32): 66560 float4s
        int idx = (blockIdx.x - 272) * 256 + t;
        float4* z = (float4*)zbase + idx;
        *z = (float4){0.f, 0.f, 0.f, 0.f};
    }
}

// ---------------- Kernel 2: GN finalize (in-block) + QKV proj via MFMA ----
__global__ __launch_bounds__(256) void qkv_proj(
        const float* __restrict__ x,
        const float* __restrict__ part,
        const float* __restrict__ gamma,
        const float* __restrict__ beta,
        const short* __restrict__ wfrag,
        const float* __restrict__ bq, const float* __restrict__ bk,
        const float* __restrict__ bv,
        short* __restrict__ qb, short* __restrict__ kb,
        short* __restrict__ vt) {
    __shared__ unsigned short vtile[64 * 72];
    __shared__ float sA[256], sB[256];
    __shared__ float sScale[64], sShift[64];
    int t = threadIdx.x;
    int lane = t & 63, wid = t >> 6;
    int g = lane >> 4, cl = lane & 15;
    int pixblk = blockIdx.x * 64;
    int pix0 = pixblk + wid * 16;
    int b = pixblk >> 12;

    // in-block GroupNorm finalize (redundant per block; part is L2-hot)
    {
        int c = t & 63, rr = t >> 6;
        float s = 0.f, s2 = 0.f;
        #pragma unroll
        for (int k = 0; k < 16; ++k) {
            int blk = b * 64 + rr + 4 * k;
            s  += part[blk * 128 + c];
            s2 += part[blk * 128 + 64 + c];
        }
        sA[t] = s; sB[t] = s2;
        __syncthreads();
        if (t < 64) {
            sA[t] = sA[t] + sA[64 + t] + sA[128 + t] + sA[192 + t];
            sB[t] = sB[t] + sB[64 + t] + sB[128 + t] + sB[192 + t];
        }
        __syncthreads();
        if (t < 64) {
            int gg = t >> 1;
            float sumg  = sA[gg * 2] + sA[gg * 2 + 1];
            float sum2g = sB[gg * 2] + sB[gg * 2 + 1];
            const float n = (float)(NN * 2);
            float mean = sumg / n;
            float var  = sum2g / n - mean * mean;
            float r = rsqrtf(var + EPS);
            float a = gamma[t] * r;
            sScale[t] = a;
            sShift[t] = beta[t] - mean * a;
        }
        __syncthreads();
    }

    const float* xp = x + (size_t)(pix0 + cl) * CC + g * 8;
    float4 x00 = *(const float4*)(xp);
    float4 x01 = *(const float4*)(xp + 4);
    float4 x10 = *(const float4*)(xp + 32);
    float4 x11 = *(const float4*)(xp + 36);
    float4 s00 = *(const float4*)(&sScale[g * 8]);
    float4 s01 = *(const float4*)(&sScale[g * 8 + 4]);
    float4 s10 = *(const float4*)(&sScale[g * 8 + 32]);
    float4 s11 = *(const float4*)(&sScale[g * 8 + 36]);
    float4 f00 = *(const float4*)(&sShift[g * 8]);
    float4 f01 = *(const float4*)(&sShift[g * 8 + 4]);
    float4 f10 = *(const float4*)(&sShift[g * 8 + 32]);
    float4 f11 = *(const float4*)(&sShift[g * 8 + 36]);

    union { bf16x8 v; unsigned u[4]; } af0, af1;
    af0.u[0] = packbf(x00.x * s00.x + f00.x, x00.y * s00.y + f00.y);
    af0.u[1] = packbf(x00.z * s00.z + f00.z, x00.w * s00.w + f00.w);
    af0.u[2] = packbf(x01.x * s01.x + f01.x, x01.y * s01.y + f01.y);
    af0.u[3] = packbf(x01.z * s01.z + f01.z, x01.w * s01.w + f01.w);
    af1.u[0] = packbf(x10.x * s10.x + f10.x, x10.y * s10.y + f10.y);
    af1.u[1] = packbf(x10.z * s10.z + f10.z, x10.w * s10.w + f10.w);
    af1.u[2] = packbf(x11.x * s11.x + f11.x, x11.y * s11.y + f11.y);
    af1.u[3] = packbf(x11.z * s11.z + f11.z, x11.w * s11.w + f11.w);

    #pragma unroll
    for (int m = 0; m < 3; ++m) {
        const float* bias = (m == 0) ? bq : (m == 1) ? bk : bv;
        #pragma unroll
        for (int dt = 0; dt < 4; ++dt) {
            bf16x8 w0 = *(const bf16x8*)(wfrag + (size_t)(((m * 4 + dt) * 2 + 0) * 64 + lane) * 8);
            bf16x8 w1 = *(const bf16x8*)(wfrag + (size_t)(((m * 4 + dt) * 2 + 1) * 64 + lane) * 8);
            f32x4 z = (f32x4){0.f, 0.f, 0.f, 0.f};
            z = __builtin_amdgcn_mfma_f32_16x16x32_bf16(af0.v, w0, z, 0, 0, 0);
            z = __builtin_amdgcn_mfma_f32_16x16x32_bf16(af1.v, w1, z, 0, 0, 0);
            float bias_d = bias[dt * 16 + cl];
            if (m == 0) {
                #pragma unroll
                for (int r = 0; r < 4; ++r)
                    qb[(size_t)(pix0 + 4 * g + r) * CC + dt * 16 + cl] =
                        (short)bf16bits((z[r] + bias_d) * QSCALE);
            } else if (m == 1) {
                #pragma unroll
                for (int r = 0; r < 4; ++r)
                    kb[(size_t)(pix0 + 4 * g + r) * CC + dt * 16 + cl] =
                        (short)bf16bits(z[r] + bias_d);
            } else {
                #pragma unroll
                for (int r = 0; r < 4; ++r)
                    vtile[(dt * 16 + cl) * 72 + wid * 16 + 4 * g + r] =
                        bf16bits(z[r] + bias_d);
            }
        }
    }
    __syncthreads();
    {
        int d = t >> 2, seg = t & 3;
        uint4 v0 = *(const uint4*)(vtile + d * 72 + seg * 16);
        uint4 v1 = *(const uint4*)(vtile + d * 72 + seg * 16 + 8);
        uint4* dst = (uint4*)(vt + ((size_t)(b * 64 + d)) * NN + pixblk + seg * 16);
        dst[0] = v0; dst[1] = v1;
    }
}

// ---------------- Kernel 3: flash attention, atomic split-K accumulation --
// grid = 64 qblocks * KSPLIT(16) = 1024; block = 4 waves = 256 q; 64 q/wave.
// Fixed-max softmax -> partials are LINEAR: accumulate unnormalized O and S
// via native f32 atomics; no partial buffers, no merge pass.
__global__ __launch_bounds__(256, 3) void attn_mfma64(
        const short* __restrict__ qb, const short* __restrict__ kb,
        const short* __restrict__ vt,
        float* __restrict__ oaccum, float* __restrict__ saccum) {
    __shared__ short lds[3][2][64 * 64];   // [buf][K|V][64 rows][64 shorts]
    const int t = threadIdx.x;
    const int lane = t & 63;
    const int wid  = t >> 6;               // 0..3
    const int hi  = lane >> 5;
    const int l31 = lane & 31;
    const int r7  = l31 & 7;
    const int kseg   = blockIdx.x % KSPLIT;
    const int qblock = blockIdx.x / KSPLIT;       // 0..63 (256 q each)
    const int b = qblock >> 4;                    // 16 qblocks per batch
    const int key0 = kseg * (NN / KSPLIT);        // within batch
    const int qbase0 = qblock * 256 + wid * 64;   // first query of this wave

    // Q B-fragments: lane: q=l31 within q-col block qc, ch=16s+8hi+j
    bf16x8 qf[2][4];
    const short* qp = qb + (size_t)(qbase0 + l31) * CC + 8 * hi;
    #pragma unroll
    for (int qc = 0; qc < 2; ++qc)
        #pragma unroll
        for (int s = 0; s < 4; ++s)
            qf[qc][s] = *(const bf16x8*)(qp + qc * 32 * CC + 16 * s);

    // staging geometry: 256 threads cover 32 rows x 8 col16-units per round
    const int srow = t >> 3;               // 0..31
    const int scol = t & 7;
    const short* kS = kb + ((size_t)b * NN + key0) * CC;   // K rows: 64 shorts
    const short* vS = vt + ((size_t)b * CC) * NN + key0;   // V^T rows: stride NN

    f32x16 oacc00, oacc01, oacc10, oacc11;
    #pragma unroll
    for (int r = 0; r < 16; ++r) {
        oacc00[r] = 0.f; oacc01[r] = 0.f; oacc10[r] = 0.f; oacc11[r] = 0.f;
    }
    float psum0 = 0.f, psum1 = 0.f;

    // 4 global_load_lds per thread per stage (2 K + 2 V)
    auto stage = [&](int ck, int bsel) {
        #pragma unroll
        for (int r = 0; r < 2; ++r) {
            int row = srow + 32 * r;
            const short* src = kS + (size_t)(ck * 64 + row) * CC + (scol ^ (row & 7)) * 8;
            __builtin_amdgcn_global_load_lds(
                (const __attribute__((address_space(1))) void*)src,
                (__attribute__((address_space(3))) void*)&lds[bsel][0][(r * 32 + wid * 8) * 64],
                16, 0, 0);
        }
        #pragma unroll
        for (int r = 0; r < 2; ++r) {
            int row = srow + 32 * r;
            const short* src = vS + (size_t)row * NN + ck * 64 + (scol ^ (row & 7)) * 8;
            __builtin_amdgcn_global_load_lds(
                (const __attribute__((address_space(1))) void*)src,
                (__attribute__((address_space(3))) void*)&lds[bsel][1][(r * 32 + wid * 8) * 64],
                16, 0, 0);
        }
    };

    auto subbody = [&](const short* kB, const short* vB, int ks) {
        bf16x8 kf[4];
        #pragma unroll
        for (int s = 0; s < 4; ++s)
            kf[s] = *(const bf16x8*)(kB + (32 * ks + l31) * 64 + ((2 * s + hi) ^ r7) * 8);
        bf16x8 vf0 = *(const bf16x8*)(vB + (l31) * 64      + ((4 * ks + 0 + hi) ^ r7) * 8);
        bf16x8 vf1 = *(const bf16x8*)(vB + (32 + l31) * 64 + ((4 * ks + 0 + hi) ^ r7) * 8);
        bf16x8 vf2 = *(const bf16x8*)(vB + (l31) * 64      + ((4 * ks + 2 + hi) ^ r7) * 8);
        bf16x8 vf3 = *(const bf16x8*)(vB + (32 + l31) * 64 + ((4 * ks + 2 + hi) ^ r7) * 8);
        // ---- qc = 0 ----
        {
            f32x16 st;
            #pragma unroll
            for (int r = 0; r < 16; ++r) st[r] = 0.f;
            #pragma unroll
            for (int s = 0; s < 4; ++s)
                st = __builtin_amdgcn_mfma_f32_32x32x16_bf16(kf[s], qf[0][s], st, 0, 0, 0);
            float ps = 0.f;
            #pragma unroll
            for (int r = 0; r < 16; ++r) { st[r] = exp2g(st[r]); ps += st[r]; }
            psum0 += ps;
            unsigned w[8];
            #pragma unroll
            for (int i = 0; i < 8; ++i) w[i] = cvtpk(st[2 * i], st[2 * i + 1]);
            PSWAP(w[0], w[2]); PSWAP(w[1], w[3]);
            PSWAP(w[4], w[6]); PSWAP(w[5], w[7]);
            union { bf16x8 v; unsigned u[4]; } pa0, pa1;
            pa0.u[0] = w[0]; pa0.u[1] = w[1]; pa0.u[2] = w[2]; pa0.u[3] = w[3];
            pa1.u[0] = w[4]; pa1.u[1] = w[5]; pa1.u[2] = w[6]; pa1.u[3] = w[7];
            oacc00 = __builtin_amdgcn_mfma_f32_32x32x16_bf16(pa0.v, vf0, oacc00, 0, 0, 0);
            oacc01 = __builtin_amdgcn_mfma_f32_32x32x16_bf16(pa0.v, vf1, oacc01, 0, 0, 0);
            oacc00 = __builtin_amdgcn_mfma_f32_32x32x16_bf16(pa1.v, vf2, oacc00, 0, 0, 0);
            oacc01 = __builtin_amdgcn_mfma_f32_32x32x16_bf16(pa1.v, vf3, oacc01, 0, 0, 0);
        }
        // ---- qc = 1 ----
        {
            f32x16 st;
            #pragma unroll
            for (int r = 0; r < 16; ++r) st[r] = 0.f;
            #pragma unroll
            for (int s = 0; s < 4; ++s)
                st = __builtin_amdgcn_mfma_f32_32x32x16_bf16(kf[s], qf[1][s], st, 0, 0, 0);
            float ps = 0.f;
            #pragma unroll
            for (int r = 0; r < 16; ++r) { st[r] = exp2g(st[r]); ps += st[r]; }
            psum1 += ps;
            unsigned w[8];
            #pragma unroll
            for (int i = 0; i < 8; ++i) w[i] = cvtpk(st[2 * i], st[2 * i + 1]);
            PSWAP(w[0], w[2]); PSWAP(w[1], w[3]);
            PSWAP(w[4], w[6]); PSWAP(w[5], w[7]);
            union { bf16x8 v; unsigned u[4]; } pa0, pa1;
            pa0.u[0] = w[0]; pa0.u[1] = w[1]; pa0.u[2] = w[2]; pa0.u[3] = w[3];
            pa1.u[0] = w[4]; pa1.u[1] = w[5]; pa1.u[2] = w[6]; pa1.u[3] = w[7];
            oacc10 = __builtin_amdgcn_mfma_f32_32x32x16_bf16(pa0.v, vf0, oacc10, 0, 0, 0);
            oacc11 = __builtin_amdgcn_mfma_f32_32x32x16_bf16(pa0.v, vf1, oacc11, 0, 0, 0);
            oacc10 = __builtin_amdgcn_mfma_f32_32x32x16_bf16(pa1.v, vf2, oacc10, 0, 0, 0);
            oacc11 = __builtin_amdgcn_mfma_f32_32x32x16_bf16(pa1.v, vf3, oacc11, 0, 0, 0);
        }
    };

    // depth-2 pipeline: stage c and c+1 in flight; wait only for c (vmcnt(4))
    stage(0, 0);
    stage(1, 1);
    #pragma unroll 1
    for (int c = 0; c < NCHK - 1; ++c) {
        asm volatile("s_waitcnt vmcnt(4)" ::: "memory");   // stage(c) complete
        __builtin_amdgcn_s_barrier();
        if (c + 2 < NCHK) stage(c + 2, (c + 2) % 3);
        const short* kB = &lds[c % 3][0][0];
        const short* vB = &lds[c % 3][1][0];
        subbody(kB, vB, 0);
        subbody(kB, vB, 1);
    }
    asm volatile("s_waitcnt vmcnt(0)" ::: "memory");
    __builtin_amdgcn_s_barrier();
    {
        const int c = NCHK - 1;
        const short* kB = &lds[c % 3][0][0];
        const short* vB = &lds[c % 3][1][0];
        subbody(kB, vB, 0);
        subbody(kB, vB, 1);
    }

    // atomic accumulation of unnormalized partials (linear merge)
    #pragma unroll
    for (int r = 0; r < 16; ++r) {
        int row = (r & 3) + 8 * (r >> 2) + 4 * hi;
        float* p0 = oaccum + (size_t)(qbase0 + row) * CC + l31;
        unsafeAtomicAdd(p0,      oacc00[r]);
        unsafeAtomicAdd(p0 + 32, oacc01[r]);
        float* p1 = oaccum + (size_t)(qbase0 + 32 + row) * CC + l31;
        unsafeAtomicAdd(p1,      oacc10[r]);
        unsafeAtomicAdd(p1 + 32, oacc11[r]);
    }
    unsafeAtomicAdd(saccum + qbase0 + l31,      psum0);
    unsafeAtomicAdd(saccum + qbase0 + 32 + l31, psum1);
}

// ---------------- Kernel 4: normalize + out-proj + residual ---------------
__global__ __launch_bounds__(256) void attn_outproj(
        const float* __restrict__ oaccum, const float* __restrict__ saccum,
        const short* __restrict__ wfrag,
        const float* __restrict__ x,
        const float* __restrict__ bo,
        float* __restrict__ out) {
    int t = threadIdx.x;
    int lane = t & 63, wid = t >> 6;
    int hi = lane >> 5, l31 = lane & 31;
    int qtile = blockIdx.x * 4 + wid;
    int q0 = qtile * QBLK;

    float inv = 1.f / saccum[q0 + l31];

    // A-frag: lane holds O[q=l31][ch = 16s + 8hi + j]
    const float* ob = oaccum + (size_t)(q0 + l31) * CC + 8 * hi;
    union { bf16x8 v; unsigned u[4]; } af[4];
    #pragma unroll
    for (int s = 0; s < 4; ++s) {
        float4 a0 = *(const float4*)(ob + 16 * s);
        float4 a1 = *(const float4*)(ob + 16 * s + 4);
        af[s].u[0] = cvtpk(a0.x * inv, a0.y * inv);
        af[s].u[1] = cvtpk(a0.z * inv, a0.w * inv);
        af[s].u[2] = cvtpk(a1.x * inv, a1.y * inv);
        af[s].u[3] = cvtpk(a1.z * inv, a1.w * inv);
    }

    const short* w32 = wfrag + 12288;
    f32x16 z0, z1;
    #pragma unroll
    for (int r = 0; r < 16; ++r) { z0[r] = 0.f; z1[r] = 0.f; }
    #pragma unroll
    for (int s = 0; s < 4; ++s) {
        bf16x8 wb0 = *(const bf16x8*)(w32 + (size_t)((s * 2 + 0) * 64 + lane) * 8);
        bf16x8 wb1 = *(const bf16x8*)(w32 + (size_t)((s * 2 + 1) * 64 + lane) * 8);
        z0 = __builtin_amdgcn_mfma_f32_32x32x16_bf16(af[s].v, wb0, z0, 0, 0, 0);
        z1 = __builtin_amdgcn_mfma_f32_32x32x16_bf16(af[s].v, wb1, z1, 0, 0, 0);
    }
    float bo0 = bo[l31], bo1 = bo[32 + l31];
    #pragma unroll
    for (int r = 0; r < 16; ++r) {
        int row = (r & 3) + 8 * (r >> 2) + 4 * hi;
        size_t i0 = (size_t)(q0 + row) * CC + l31;
        out[i0]      = x[i0]      + z0[r] + bo0;
        out[i0 + 32] = x[i0 + 32] + z1[r] + bo1;
    }
}

extern "C" void kernel_launch(void* const* d_in, const int* in_sizes, int n_in,
                              void* d_out, int out_size, void* d_ws, size_t ws_size,
                              hipStream_t stream) {
    const float* x     = (const float*)d_in[0];
    const float* gamma = (const float*)d_in[1];
    const float* beta  = (const float*)d_in[2];
    const float* wq    = (const float*)d_in[3];
    const float* bq    = (const float*)d_in[4];
    const float* wk    = (const float*)d_in[5];
    const float* bk    = (const float*)d_in[6];
    const float* wv    = (const float*)d_in[7];
    const float* bv    = (const float*)d_in[8];
    const float* wo    = (const float*)d_in[9];
    const float* bo    = (const float*)d_in[10];
    float* out = (float*)d_out;

    float* ws     = (float*)d_ws;
    float* part   = ws;                                  // 32768 f32
    short* wfrag  = (short*)(part + 32768);              // 16384 bf16
    short* qb     = wfrag + 16384;
    short* kbp    = qb  + (size_t)NPIX * CC;
    short* vtp    = kbp + (size_t)NPIX * CC;
    float* oaccum = (float*)(vtp + (size_t)NPIX * CC);   // NPIX*CC f32
    float* saccum = oaccum + (size_t)NPIX * CC;          // NPIX f32 (contig for zeroing)

    hipLaunchKernelGGL(gn_wt, dim3(532), dim3(256), 0, stream,
                       x, part, wq, wk, wv, wo, wfrag, oaccum);
    hipLaunchKernelGGL(qkv_proj, dim3(256), dim3(256), 0, stream,
                       x, part, gamma, beta, wfrag, bq, bk, bv, qb, kbp, vtp);
    hipLaunchKernelGGL(attn_mfma64, dim3(64 * KSPLIT), dim3(256), 0, stream,
                       qb, kbp, vtp, oaccum, saccum);
    hipLaunchKernelGGL(attn_outproj, dim3(NQT32 / 4), dim3(256), 0, stream,
                       oaccum, saccum, wfrag, x, bo, out);
}

// Round 13
// 46.782 us; speedup vs baseline: 2.5455x; 2.5455x over previous
//
#include <hip/hip_runtime.h>
#include <math.h>

#define BB 4
#define HH 64
#define WW 64
#define CC 64
#define NN (HH*WW)          // 4096 pixels per batch
#define NPIX (BB*NN)        // 16384 total pixels
#define EPS 1e-3f
#define QBLK 32
#define KSPLIT 8
#define NQT32 (NPIX/QBLK)   // 512 query tiles of 32
#define CHUNK 128
#define NCHK ((NN/KSPLIT)/CHUNK)   // 4 chunks of 128 keys per segment

using bf16x8 = __attribute__((ext_vector_type(8))) short;
using f32x4  = __attribute__((ext_vector_type(4))) float;
using f32x16 = __attribute__((ext_vector_type(16))) float;

__device__ inline unsigned short bf16bits(float f) {
    union { float f; unsigned u; } a; a.f = f;
    unsigned r = a.u + 0x7fffu + ((a.u >> 16) & 1u);   // RNE
    return (unsigned short)(r >> 16);
}
__device__ inline unsigned packbf(float lo, float hi) {
    return (unsigned)bf16bits(lo) | ((unsigned)bf16bits(hi) << 16);
}
__device__ inline unsigned cvtpk(float lo, float hi) {
    unsigned r;
    asm("v_cvt_pk_bf16_f32 %0, %1, %2" : "=v"(r) : "v"(lo), "v"(hi));
    return r;
}
#define PSWAP(a, b) asm("v_permlane32_swap_b32 %0, %1" : "+v"(a), "+v"(b))

// raw 2^x (no libm edge handling; inputs are bounded scores)
__device__ __forceinline__ float exp2g(float x) {
    float r;
    asm("v_exp_f32 %0, %1" : "=v"(r) : "v"(x));
    return r;
}

// Q pre-scale: (1/8) * log2(e) so attention softmax uses 2^x directly
#define QSCALE 0.18033688011112042f

// ---------------- Kernel 1: GroupNorm partial sums + weight prep ----------
__global__ __launch_bounds__(256) void gn_wt(const float* __restrict__ x,
                                             float* __restrict__ part,
                                             const float* __restrict__ wq,
                                             const float* __restrict__ wk,
                                             const float* __restrict__ wv,
                                             const float* __restrict__ wo,
                                             short* __restrict__ wfrag) {
    int t = threadIdx.x;
    if (blockIdx.x < 256) {
        int c = t & 63, rr = t >> 6;
        int p0 = blockIdx.x * 64;
        float s = 0.f, s2 = 0.f;
        #pragma unroll
        for (int k = 0; k < 16; ++k) {
            float v = x[(size_t)(p0 + rr + 4 * k) * CC + c];
            s += v; s2 += v * v;
        }
        __shared__ float sA[256], sB[256];
        sA[t] = s; sB[t] = s2;
        __syncthreads();
        if (t < 64) {
            float fs  = sA[t] + sA[64 + t] + sA[128 + t] + sA[192 + t];
            float fs2 = sB[t] + sB[64 + t] + sB[128 + t] + sB[192 + t];
            part[blockIdx.x * 128 + t]      = fs;
            part[blockIdx.x * 128 + 64 + t] = fs2;
        }
    } else {
        const float* mats[3] = {wq, wk, wv};
        int i0 = (blockIdx.x - 256) * 256 + t;
        for (int e = i0; e < 12288; e += 16 * 256) {
            int m = e >> 12;
            int r = e & 4095;
            int dt = r >> 10, h = (r >> 9) & 1, lane = (r >> 3) & 63, j = r & 7;
            int g = lane >> 4, cl = lane & 15;
            float v = mats[m][(h * 32 + g * 8 + j) * 64 + dt * 16 + cl];
            wfrag[e] = (short)bf16bits(v);
        }
        for (int e = i0; e < 4096; e += 16 * 256) {
            int j = e & 7, lane = (e >> 3) & 63, dt = (e >> 9) & 1, s = e >> 10;
            int hi = lane >> 5, l31 = lane & 31;
            float v = wo[(8 * hi + 16 * s + j) * 64 + dt * 32 + l31];
            wfrag[12288 + e] = (short)bf16bits(v);
        }
    }
}

// ---------------- Kernel 2: GN finalize (in-block) + QKV proj via MFMA ----
__global__ __launch_bounds__(256) void qkv_proj(
        const float* __restrict__ x,
        const float* __restrict__ part,
        const float* __restrict__ gamma,
        const float* __restrict__ beta,
        const short* __restrict__ wfrag,
        const float* __restrict__ bq, const float* __restrict__ bk,
        const float* __restrict__ bv,
        short* __restrict__ qb, short* __restrict__ kb,
        short* __restrict__ vt) {
    __shared__ unsigned short vtile[64 * 72];
    __shared__ float sA[256], sB[256];
    __shared__ float sScale[64], sShift[64];
    int t = threadIdx.x;
    int lane = t & 63, wid = t >> 6;
    int g = lane >> 4, cl = lane & 15;
    int pixblk = blockIdx.x * 64;
    int pix0 = pixblk + wid * 16;
    int b = pixblk >> 12;

    // in-block GroupNorm finalize (redundant per block; part is L2-hot)
    {
        int c = t & 63, rr = t >> 6;
        float s = 0.f, s2 = 0.f;
        #pragma unroll
        for (int k = 0; k < 16; ++k) {
            int blk = b * 64 + rr + 4 * k;
            s  += part[blk * 128 + c];
            s2 += part[blk * 128 + 64 + c];
        }
        sA[t] = s; sB[t] = s2;
        __syncthreads();
        if (t < 64) {
            sA[t] = sA[t] + sA[64 + t] + sA[128 + t] + sA[192 + t];
            sB[t] = sB[t] + sB[64 + t] + sB[128 + t] + sB[192 + t];
        }
        __syncthreads();
        if (t < 64) {
            int gg = t >> 1;
            float sumg  = sA[gg * 2] + sA[gg * 2 + 1];
            float sum2g = sB[gg * 2] + sB[gg * 2 + 1];
            const float n = (float)(NN * 2);
            float mean = sumg / n;
            float var  = sum2g / n - mean * mean;
            float r = rsqrtf(var + EPS);
            float a = gamma[t] * r;
            sScale[t] = a;
            sShift[t] = beta[t] - mean * a;
        }
        __syncthreads();
    }

    const float* xp = x + (size_t)(pix0 + cl) * CC + g * 8;
    float4 x00 = *(const float4*)(xp);
    float4 x01 = *(const float4*)(xp + 4);
    float4 x10 = *(const float4*)(xp + 32);
    float4 x11 = *(const float4*)(xp + 36);
    float4 s00 = *(const float4*)(&sScale[g * 8]);
    float4 s01 = *(const float4*)(&sScale[g * 8 + 4]);
    float4 s10 = *(const float4*)(&sScale[g * 8 + 32]);
    float4 s11 = *(const float4*)(&sScale[g * 8 + 36]);
    float4 f00 = *(const float4*)(&sShift[g * 8]);
    float4 f01 = *(const float4*)(&sShift[g * 8 + 4]);
    float4 f10 = *(const float4*)(&sShift[g * 8 + 32]);
    float4 f11 = *(const float4*)(&sShift[g * 8 + 36]);

    union { bf16x8 v; unsigned u[4]; } af0, af1;
    af0.u[0] = packbf(x00.x * s00.x + f00.x, x00.y * s00.y + f00.y);
    af0.u[1] = packbf(x00.z * s00.z + f00.z, x00.w * s00.w + f00.w);
    af0.u[2] = packbf(x01.x * s01.x + f01.x, x01.y * s01.y + f01.y);
    af0.u[3] = packbf(x01.z * s01.z + f01.z, x01.w * s01.w + f01.w);
    af1.u[0] = packbf(x10.x * s10.x + f10.x, x10.y * s10.y + f10.y);
    af1.u[1] = packbf(x10.z * s10.z + f10.z, x10.w * s10.w + f10.w);
    af1.u[2] = packbf(x11.x * s11.x + f11.x, x11.y * s11.y + f11.y);
    af1.u[3] = packbf(x11.z * s11.z + f11.z, x11.w * s11.w + f11.w);

    #pragma unroll
    for (int m = 0; m < 3; ++m) {
        const float* bias = (m == 0) ? bq : (m == 1) ? bk : bv;
        #pragma unroll
        for (int dt = 0; dt < 4; ++dt) {
            bf16x8 w0 = *(const bf16x8*)(wfrag + (size_t)(((m * 4 + dt) * 2 + 0) * 64 + lane) * 8);
            bf16x8 w1 = *(const bf16x8*)(wfrag + (size_t)(((m * 4 + dt) * 2 + 1) * 64 + lane) * 8);
            f32x4 z = (f32x4){0.f, 0.f, 0.f, 0.f};
            z = __builtin_amdgcn_mfma_f32_16x16x32_bf16(af0.v, w0, z, 0, 0, 0);
            z = __builtin_amdgcn_mfma_f32_16x16x32_bf16(af1.v, w1, z, 0, 0, 0);
            float bias_d = bias[dt * 16 + cl];
            if (m == 0) {
                #pragma unroll
                for (int r = 0; r < 4; ++r)
                    qb[(size_t)(pix0 + 4 * g + r) * CC + dt * 16 + cl] =
                        (short)bf16bits((z[r] + bias_d) * QSCALE);
            } else if (m == 1) {
                #pragma unroll
                for (int r = 0; r < 4; ++r)
                    kb[(size_t)(pix0 + 4 * g + r) * CC + dt * 16 + cl] =
                        (short)bf16bits(z[r] + bias_d);
            } else {
                #pragma unroll
                for (int r = 0; r < 4; ++r)
                    vtile[(dt * 16 + cl) * 72 + wid * 16 + 4 * g + r] =
                        bf16bits(z[r] + bias_d);
            }
        }
    }
    __syncthreads();
    {
        int d = t >> 2, seg = t & 3;
        uint4 v0 = *(const uint4*)(vtile + d * 72 + seg * 16);
        uint4 v1 = *(const uint4*)(vtile + d * 72 + seg * 16 + 8);
        uint4* dst = (uint4*)(vt + ((size_t)(b * 64 + d)) * NN + pixblk + seg * 16);
        dst[0] = v0; dst[1] = v1;
    }
}

// ---------------- Kernel 3: flash attention, 128-key chunks ---------------
// grid = 64 qblocks * KSPLIT = 512; block = 4 waves = 256 q; 64 q/wave.
// 2 LDS bufs x 32KB (K[128][64] + V[64][128], XOR-swizzled source); one
// barrier per 128-key chunk (4 total); setprio around MFMA clusters.
__global__ __launch_bounds__(256, 2) void attn_mfma64(
        const short* __restrict__ qb, const short* __restrict__ kb,
        const short* __restrict__ vt,
        unsigned* __restrict__ obf, float* __restrict__ msb) {
    __shared__ short lds[2][2][128 * 64];   // [buf][K|V]; K=[128][64], V=[64][128]
    const int t = threadIdx.x;
    const int lane = t & 63;
    const int wid  = t >> 6;               // 0..3
    const int hi  = lane >> 5;
    const int l31 = lane & 31;
    const int r7  = l31 & 7;
    const int kseg   = blockIdx.x % KSPLIT;
    const int qblock = blockIdx.x / KSPLIT;       // 0..63 (256 q each)
    const int qt0 = qblock * 8 + wid * 2;         // first 32-q tile of this wave
    const int b = qblock >> 4;                    // 16 qblocks per batch
    const int key0 = kseg * (NN / KSPLIT);        // within batch

    // Q B-fragments: lane: q=l31 within q-col block qc, ch=16s+8hi+j
    bf16x8 qf[2][4];
    const short* qp = qb + (size_t)(qblock * 256 + wid * 64 + l31) * CC + 8 * hi;
    #pragma unroll
    for (int qc = 0; qc < 2; ++qc)
        #pragma unroll
        for (int s = 0; s < 4; ++s)
            qf[qc][s] = *(const bf16x8*)(qp + qc * 32 * CC + 16 * s);

    // staging geometry
    const int srowK = t >> 3;              // 0..31 (K rows per round)
    const int scolK = t & 7;               // 8 units of 16B per K row
    const int srowV = t >> 4;              // 0..15 (V rows per round)
    const int scolV = t & 15;              // 16 units of 16B per V row
    const short* kS = kb + ((size_t)b * NN + key0) * CC;   // K rows: 64 shorts
    const short* vS = vt + ((size_t)b * CC) * NN + key0;   // V^T rows: stride NN

    f32x16 oacc00, oacc01, oacc10, oacc11;
    #pragma unroll
    for (int r = 0; r < 16; ++r) {
        oacc00[r] = 0.f; oacc01[r] = 0.f; oacc10[r] = 0.f; oacc11[r] = 0.f;
    }
    float psum0 = 0.f, psum1 = 0.f;

    // 8 global_load_lds per thread per stage (4 K + 4 V), swizzled source
    auto stage = [&](int ck, int bsel) {
        #pragma unroll
        for (int r = 0; r < 4; ++r) {
            int row = srowK + 32 * r;      // 0..127
            const short* src = kS + (size_t)(ck * CHUNK + row) * CC + (scolK ^ (row & 7)) * 8;
            __builtin_amdgcn_global_load_lds(
                (const __attribute__((address_space(1))) void*)src,
                (__attribute__((address_space(3))) void*)&lds[bsel][0][(r * 32 + wid * 8) * 64],
                16, 0, 0);
        }
        #pragma unroll
        for (int r = 0; r < 4; ++r) {
            int row = srowV + 16 * r;      // 0..63 (channel)
            const short* src = vS + (size_t)row * NN + ck * CHUNK + (scolV ^ (row & 7)) * 8;
            __builtin_amdgcn_global_load_lds(
                (const __attribute__((address_space(1))) void*)src,
                (__attribute__((address_space(3))) void*)&lds[bsel][1][(r * 16 + wid * 4) * 128],
                16, 0, 0);
        }
    };

    // one 32-key tile (kst in 0..3) against both q-column blocks
    auto subbody = [&](const short* kB, const short* vB, int kst) {
        bf16x8 kf[4];
        #pragma unroll
        for (int s = 0; s < 4; ++s)
            kf[s] = *(const bf16x8*)(kB + (32 * kst + l31) * 64 + ((2 * s + hi) ^ r7) * 8);
        bf16x8 vf0 = *(const bf16x8*)(vB + (l31) * 128      + ((4 * kst + 0 + hi) ^ r7) * 8);
        bf16x8 vf1 = *(const bf16x8*)(vB + (32 + l31) * 128 + ((4 * kst + 0 + hi) ^ r7) * 8);
        bf16x8 vf2 = *(const bf16x8*)(vB + (l31) * 128      + ((4 * kst + 2 + hi) ^ r7) * 8);
        bf16x8 vf3 = *(const bf16x8*)(vB + (32 + l31) * 128 + ((4 * kst + 2 + hi) ^ r7) * 8);
        // ---- qc = 0 ----
        {
            f32x16 st;
            #pragma unroll
            for (int r = 0; r < 16; ++r) st[r] = 0.f;
            __builtin_amdgcn_s_setprio(1);
            #pragma unroll
            for (int s = 0; s < 4; ++s)
                st = __builtin_amdgcn_mfma_f32_32x32x16_bf16(kf[s], qf[0][s], st, 0, 0, 0);
            __builtin_amdgcn_s_setprio(0);
            float ps = 0.f;
            #pragma unroll
            for (int r = 0; r < 16; ++r) { st[r] = exp2g(st[r]); ps += st[r]; }
            psum0 += ps;
            unsigned w[8];
            #pragma unroll
            for (int i = 0; i < 8; ++i) w[i] = cvtpk(st[2 * i], st[2 * i + 1]);
            PSWAP(w[0], w[2]); PSWAP(w[1], w[3]);
            PSWAP(w[4], w[6]); PSWAP(w[5], w[7]);
            union { bf16x8 v; unsigned u[4]; } pa0, pa1;
            pa0.u[0] = w[0]; pa0.u[1] = w[1]; pa0.u[2] = w[2]; pa0.u[3] = w[3];
            pa1.u[0] = w[4]; pa1.u[1] = w[5]; pa1.u[2] = w[6]; pa1.u[3] = w[7];
            __builtin_amdgcn_s_setprio(1);
            oacc00 = __builtin_amdgcn_mfma_f32_32x32x16_bf16(pa0.v, vf0, oacc00, 0, 0, 0);
            oacc01 = __builtin_amdgcn_mfma_f32_32x32x16_bf16(pa0.v, vf1, oacc01, 0, 0, 0);
            oacc00 = __builtin_amdgcn_mfma_f32_32x32x16_bf16(pa1.v, vf2, oacc00, 0, 0, 0);
            oacc01 = __builtin_amdgcn_mfma_f32_32x32x16_bf16(pa1.v, vf3, oacc01, 0, 0, 0);
            __builtin_amdgcn_s_setprio(0);
        }
        // ---- qc = 1 ----
        {
            f32x16 st;
            #pragma unroll
            for (int r = 0; r < 16; ++r) st[r] = 0.f;
            __builtin_amdgcn_s_setprio(1);
            #pragma unroll
            for (int s = 0; s < 4; ++s)
                st = __builtin_amdgcn_mfma_f32_32x32x16_bf16(kf[s], qf[1][s], st, 0, 0, 0);
            __builtin_amdgcn_s_setprio(0);
            float ps = 0.f;
            #pragma unroll
            for (int r = 0; r < 16; ++r) { st[r] = exp2g(st[r]); ps += st[r]; }
            psum1 += ps;
            unsigned w[8];
            #pragma unroll
            for (int i = 0; i < 8; ++i) w[i] = cvtpk(st[2 * i], st[2 * i + 1]);
            PSWAP(w[0], w[2]); PSWAP(w[1], w[3]);
            PSWAP(w[4], w[6]); PSWAP(w[5], w[7]);
            union { bf16x8 v; unsigned u[4]; } pa0, pa1;
            pa0.u[0] = w[0]; pa0.u[1] = w[1]; pa0.u[2] = w[2]; pa0.u[3] = w[3];
            pa1.u[0] = w[4]; pa1.u[1] = w[5]; pa1.u[2] = w[6]; pa1.u[3] = w[7];
            __builtin_amdgcn_s_setprio(1);
            oacc10 = __builtin_amdgcn_mfma_f32_32x32x16_bf16(pa0.v, vf0, oacc10, 0, 0, 0);
            oacc11 = __builtin_amdgcn_mfma_f32_32x32x16_bf16(pa0.v, vf1, oacc11, 0, 0, 0);
            oacc10 = __builtin_amdgcn_mfma_f32_32x32x16_bf16(pa1.v, vf2, oacc10, 0, 0, 0);
            oacc11 = __builtin_amdgcn_mfma_f32_32x32x16_bf16(pa1.v, vf3, oacc11, 0, 0, 0);
            __builtin_amdgcn_s_setprio(0);
        }
    };

    stage(0, 0);
    #pragma unroll 1
    for (int c = 0; c < NCHK; ++c) {
        asm volatile("s_waitcnt vmcnt(0)" ::: "memory");   // stage(c) landed
        __syncthreads();                                    // visible to all waves
        if (c + 1 < NCHK) stage(c + 1, (c + 1) & 1);
        const short* kB = &lds[c & 1][0][0];
        const short* vB = &lds[c & 1][1][0];
        subbody(kB, vB, 0);
        subbody(kB, vB, 1);
        subbody(kB, vB, 2);
        subbody(kB, vB, 3);
    }

    // store partial O packed: word(row,q) = (O[row][l31], O[row][l31+32])
    {
        int task = (qt0 + 0) * KSPLIT + kseg;
        unsigned* ob32 = obf + (size_t)task * 1024;
        #pragma unroll
        for (int r = 0; r < 16; ++r) {
            int row = (r & 3) + 8 * (r >> 2) + 4 * hi;     // query row
            ob32[row * 32 + l31] = cvtpk(oacc00[r], oacc01[r]);
        }
        msb[task * 64 + lane] = psum0;
    }
    {
        int task = (qt0 + 1) * KSPLIT + kseg;
        unsigned* ob32 = obf + (size_t)task * 1024;
        #pragma unroll
        for (int r = 0; r < 16; ++r) {
            int row = (r & 3) + 8 * (r >> 2) + 4 * hi;
            ob32[row * 32 + l31] = cvtpk(oacc10[r], oacc11[r]);
        }
        msb[task * 64 + lane] = psum1;
    }
}

// ---------------- Kernel 4: merge partials + out-proj + residual ---------
__device__ __forceinline__ void acc2(float& lo_acc, float& hi_acc, unsigned u) {
    union { unsigned u; float f; } a, b;
    a.u = u << 16; b.u = u & 0xffff0000u;
    lo_acc += a.f; hi_acc += b.f;
}

__global__ __launch_bounds__(256) void attn_merge_outproj(
        const unsigned* __restrict__ obf, const float* __restrict__ msb,
        const short* __restrict__ wfrag,
        const float* __restrict__ x,
        const float* __restrict__ bo,
        float* __restrict__ out) {
    int t = threadIdx.x;
    int lane = t & 63, wid = t >> 6;
    int hi = lane >> 5, l31 = lane & 31;
    int qtile = blockIdx.x * 4 + wid;

    float stot = 0.f;
    #pragma unroll
    for (int s = 0; s < KSPLIT; ++s) {
        stot += msb[(qtile * KSPLIT + s) * 64 + l31]
              + msb[(qtile * KSPLIT + s) * 64 + 32 + l31];
    }
    float inv = 1.f / stot;

    float oa[4][8];
    #pragma unroll
    for (int s = 0; s < 4; ++s)
        #pragma unroll
        for (int j = 0; j < 8; ++j) oa[s][j] = 0.f;
    #pragma unroll 4
    for (int ks = 0; ks < KSPLIT; ++ks) {
        const unsigned* base = obf + (size_t)(qtile * KSPLIT + ks) * 1024 + l31 * 32 + 8 * hi;
        uint4 wa = *(const uint4*)(base);
        uint4 wb = *(const uint4*)(base + 4);
        uint4 wc = *(const uint4*)(base + 16);
        uint4 wd = *(const uint4*)(base + 20);
        acc2(oa[0][0], oa[2][0], wa.x); acc2(oa[0][1], oa[2][1], wa.y);
        acc2(oa[0][2], oa[2][2], wa.z); acc2(oa[0][3], oa[2][3], wa.w);
        acc2(oa[0][4], oa[2][4], wb.x); acc2(oa[0][5], oa[2][5], wb.y);
        acc2(oa[0][6], oa[2][6], wb.z); acc2(oa[0][7], oa[2][7], wb.w);
        acc2(oa[1][0], oa[3][0], wc.x); acc2(oa[1][1], oa[3][1], wc.y);
        acc2(oa[1][2], oa[3][2], wc.z); acc2(oa[1][3], oa[3][3], wc.w);
        acc2(oa[1][4], oa[3][4], wd.x); acc2(oa[1][5], oa[3][5], wd.y);
        acc2(oa[1][6], oa[3][6], wd.z); acc2(oa[1][7], oa[3][7], wd.w);
    }
    union { bf16x8 v; unsigned u[4]; } af[4];
    #pragma unroll
    for (int s = 0; s < 4; ++s)
        #pragma unroll
        for (int m = 0; m < 4; ++m)
            af[s].u[m] = cvtpk(oa[s][2 * m] * inv, oa[s][2 * m + 1] * inv);

    const short* w32 = wfrag + 12288;
    f32x16 z0, z1;
    #pragma unroll
    for (int r = 0; r < 16; ++r) { z0[r] = 0.f; z1[r] = 0.f; }
    #pragma unroll
    for (int s = 0; s < 4; ++s) {
        bf16x8 wb0 = *(const bf16x8*)(w32 + (size_t)((s * 2 + 0) * 64 + lane) * 8);
        bf16x8 wb1 = *(const bf16x8*)(w32 + (size_t)((s * 2 + 1) * 64 + lane) * 8);
        z0 = __builtin_amdgcn_mfma_f32_32x32x16_bf16(af[s].v, wb0, z0, 0, 0, 0);
        z1 = __builtin_amdgcn_mfma_f32_32x32x16_bf16(af[s].v, wb1, z1, 0, 0, 0);
    }
    float bo0 = bo[l31], bo1 = bo[32 + l31];
    #pragma unroll
    for (int r = 0; r < 16; ++r) {
        int row = (r & 3) + 8 * (r >> 2) + 4 * hi;
        size_t i0 = (size_t)(qtile * QBLK + row) * CC + l31;
        out[i0]      = x[i0]      + z0[r] + bo0;
        out[i0 + 32] = x[i0 + 32] + z1[r] + bo1;
    }
}

extern "C" void kernel_launch(void* const* d_in, const int* in_sizes, int n_in,
                              void* d_out, int out_size, void* d_ws, size_t ws_size,
                              hipStream_t stream) {
    const float* x     = (const float*)d_in[0];
    const float* gamma = (const float*)d_in[1];
    const float* beta  = (const float*)d_in[2];
    const float* wq    = (const float*)d_in[3];
    const float* bq    = (const float*)d_in[4];
    const float* wk    = (const float*)d_in[5];
    const float* bk    = (const float*)d_in[6];
    const float* wv    = (const float*)d_in[7];
    const float* bv    = (const float*)d_in[8];
    const float* wo    = (const float*)d_in[9];
    const float* bo    = (const float*)d_in[10];
    float* out = (float*)d_out;

    float* ws    = (float*)d_ws;
    float* part  = ws;                                   // 32768 f32
    short* wfrag = (short*)(part + 32768);               // 16384 bf16
    short* qb    = wfrag + 16384;
    short* kbp   = qb  + (size_t)NPIX * CC;
    short* vtp   = kbp + (size_t)NPIX * CC;
    unsigned* obf = (unsigned*)(vtp + (size_t)NPIX * CC);    // NQT32*KSPLIT*1024 u32
    float* msb   = (float*)(obf + (size_t)NQT32 * KSPLIT * 1024);

    hipLaunchKernelGGL(gn_wt, dim3(272), dim3(256), 0, stream,
                       x, part, wq, wk, wv, wo, wfrag);
    hipLaunchKernelGGL(qkv_proj, dim3(256), dim3(256), 0, stream,
                       x, part, gamma, beta, wfrag, bq, bk, bv, qb, kbp, vtp);
    hipLaunchKernelGGL(attn_mfma64, dim3(64 * KSPLIT), dim3(256), 0, stream,
                       qb, kbp, vtp, obf, msb);
    hipLaunchKernelGGL(attn_merge_outproj, dim3(NQT32 / 4), dim3(256), 0, stream,
                       obf, msb, wfrag, x, bo, out);
}

// Round 14
// 45.601 us; speedup vs baseline: 2.6114x; 1.0259x over previous
//
#include <hip/hip_runtime.h>
#include <math.h>

#define BB 4
#define HH 64
#define WW 64
#define CC 64
#define NN (HH*WW)          // 4096 pixels per batch
#define NPIX (BB*NN)        // 16384 total pixels
#define EPS 1e-3f
#define QBLK 32
#define KSPLIT 8
#define NQT32 (NPIX/QBLK)   // 512 query tiles of 32
#define NCHK ((NN/KSPLIT)/64)  // 8 chunks of 64 keys per segment

using bf16x8 = __attribute__((ext_vector_type(8))) short;
using f32x4  = __attribute__((ext_vector_type(4))) float;
using f32x16 = __attribute__((ext_vector_type(16))) float;

__device__ inline unsigned short bf16bits(float f) {
    union { float f; unsigned u; } a; a.f = f;
    unsigned r = a.u + 0x7fffu + ((a.u >> 16) & 1u);   // RNE
    return (unsigned short)(r >> 16);
}
__device__ inline unsigned packbf(float lo, float hi) {
    return (unsigned)bf16bits(lo) | ((unsigned)bf16bits(hi) << 16);
}
__device__ inline unsigned cvtpk(float lo, float hi) {
    unsigned r;
    asm("v_cvt_pk_bf16_f32 %0, %1, %2" : "=v"(r) : "v"(lo), "v"(hi));
    return r;
}
#define PSWAP(a, b) asm("v_permlane32_swap_b32 %0, %1" : "+v"(a), "+v"(b))

// raw 2^x (no libm edge handling; inputs are bounded scores)
__device__ __forceinline__ float exp2g(float x) {
    float r;
    asm("v_exp_f32 %0, %1" : "=v"(r) : "v"(x));
    return r;
}

// Q pre-scale: (1/8) * log2(e) so attention softmax uses 2^x directly
#define QSCALE 0.18033688011112042f

// ---------------- Kernel 1: GroupNorm partial sums + weight prep ----------
__global__ __launch_bounds__(256) void gn_wt(const float* __restrict__ x,
                                             float* __restrict__ part,
                                             const float* __restrict__ wq,
                                             const float* __restrict__ wk,
                                             const float* __restrict__ wv,
                                             const float* __restrict__ wo,
                                             short* __restrict__ wfrag) {
    int t = threadIdx.x;
    if (blockIdx.x < 256) {
        int c = t & 63, rr = t >> 6;
        int p0 = blockIdx.x * 64;
        float s = 0.f, s2 = 0.f;
        #pragma unroll
        for (int k = 0; k < 16; ++k) {
            float v = x[(size_t)(p0 + rr + 4 * k) * CC + c];
            s += v; s2 += v * v;
        }
        __shared__ float sA[256], sB[256];
        sA[t] = s; sB[t] = s2;
        __syncthreads();
        if (t < 64) {
            float fs  = sA[t] + sA[64 + t] + sA[128 + t] + sA[192 + t];
            float fs2 = sB[t] + sB[64 + t] + sB[128 + t] + sB[192 + t];
            part[blockIdx.x * 128 + t]      = fs;
            part[blockIdx.x * 128 + 64 + t] = fs2;
        }
    } else {
        const float* mats[3] = {wq, wk, wv};
        int i0 = (blockIdx.x - 256) * 256 + t;
        for (int e = i0; e < 12288; e += 16 * 256) {
            int m = e >> 12;
            int r = e & 4095;
            int dt = r >> 10, h = (r >> 9) & 1, lane = (r >> 3) & 63, j = r & 7;
            int g = lane >> 4, cl = lane & 15;
            float v = mats[m][(h * 32 + g * 8 + j) * 64 + dt * 16 + cl];
            wfrag[e] = (short)bf16bits(v);
        }
        for (int e = i0; e < 4096; e += 16 * 256) {
            int j = e & 7, lane = (e >> 3) & 63, dt = (e >> 9) & 1, s = e >> 10;
            int hi = lane >> 5, l31 = lane & 31;
            float v = wo[(8 * hi + 16 * s + j) * 64 + dt * 32 + l31];
            wfrag[12288 + e] = (short)bf16bits(v);
        }
    }
}

// ---------------- Kernel 2: GN finalize (in-block) + QKV proj via MFMA ----
__global__ __launch_bounds__(256) void qkv_proj(
        const float* __restrict__ x,
        const float* __restrict__ part,
        const float* __restrict__ gamma,
        const float* __restrict__ beta,
        const short* __restrict__ wfrag,
        const float* __restrict__ bq, const float* __restrict__ bk,
        const float* __restrict__ bv,
        short* __restrict__ qb, short* __restrict__ kb,
        short* __restrict__ vt) {
    __shared__ unsigned short vtile[64 * 72];
    __shared__ float sA[256], sB[256];
    __shared__ float sScale[64], sShift[64];
    int t = threadIdx.x;
    int lane = t & 63, wid = t >> 6;
    int g = lane >> 4, cl = lane & 15;
    int pixblk = blockIdx.x * 64;
    int pix0 = pixblk + wid * 16;
    int b = pixblk >> 12;

    // in-block GroupNorm finalize (redundant per block; part is L2-hot)
    {
        int c = t & 63, rr = t >> 6;
        float s = 0.f, s2 = 0.f;
        #pragma unroll
        for (int k = 0; k < 16; ++k) {
            int blk = b * 64 + rr + 4 * k;
            s  += part[blk * 128 + c];
            s2 += part[blk * 128 + 64 + c];
        }
        sA[t] = s; sB[t] = s2;
        __syncthreads();
        if (t < 64) {
            sA[t] = sA[t] + sA[64 + t] + sA[128 + t] + sA[192 + t];
            sB[t] = sB[t] + sB[64 + t] + sB[128 + t] + sB[192 + t];
        }
        __syncthreads();
        if (t < 64) {
            int gg = t >> 1;
            float sumg  = sA[gg * 2] + sA[gg * 2 + 1];
            float sum2g = sB[gg * 2] + sB[gg * 2 + 1];
            const float n = (float)(NN * 2);
            float mean = sumg / n;
            float var  = sum2g / n - mean * mean;
            float r = rsqrtf(var + EPS);
            float a = gamma[t] * r;
            sScale[t] = a;
            sShift[t] = beta[t] - mean * a;
        }
        __syncthreads();
    }

    const float* xp = x + (size_t)(pix0 + cl) * CC + g * 8;
    float4 x00 = *(const float4*)(xp);
    float4 x01 = *(const float4*)(xp + 4);
    float4 x10 = *(const float4*)(xp + 32);
    float4 x11 = *(const float4*)(xp + 36);
    float4 s00 = *(const float4*)(&sScale[g * 8]);
    float4 s01 = *(const float4*)(&sScale[g * 8 + 4]);
    float4 s10 = *(const float4*)(&sScale[g * 8 + 32]);
    float4 s11 = *(const float4*)(&sScale[g * 8 + 36]);
    float4 f00 = *(const float4*)(&sShift[g * 8]);
    float4 f01 = *(const float4*)(&sShift[g * 8 + 4]);
    float4 f10 = *(const float4*)(&sShift[g * 8 + 32]);
    float4 f11 = *(const float4*)(&sShift[g * 8 + 36]);

    union { bf16x8 v; unsigned u[4]; } af0, af1;
    af0.u[0] = packbf(x00.x * s00.x + f00.x, x00.y * s00.y + f00.y);
    af0.u[1] = packbf(x00.z * s00.z + f00.z, x00.w * s00.w + f00.w);
    af0.u[2] = packbf(x01.x * s01.x + f01.x, x01.y * s01.y + f01.y);
    af0.u[3] = packbf(x01.z * s01.z + f01.z, x01.w * s01.w + f01.w);
    af1.u[0] = packbf(x10.x * s10.x + f10.x, x10.y * s10.y + f10.y);
    af1.u[1] = packbf(x10.z * s10.z + f10.z, x10.w * s10.w + f10.w);
    af1.u[2] = packbf(x11.x * s11.x + f11.x, x11.y * s11.y + f11.y);
    af1.u[3] = packbf(x11.z * s11.z + f11.z, x11.w * s11.w + f11.w);

    #pragma unroll
    for (int m = 0; m < 3; ++m) {
        const float* bias = (m == 0) ? bq : (m == 1) ? bk : bv;
        #pragma unroll
        for (int dt = 0; dt < 4; ++dt) {
            bf16x8 w0 = *(const bf16x8*)(wfrag + (size_t)(((m * 4 + dt) * 2 + 0) * 64 + lane) * 8);
            bf16x8 w1 = *(const bf16x8*)(wfrag + (size_t)(((m * 4 + dt) * 2 + 1) * 64 + lane) * 8);
            f32x4 z = (f32x4){0.f, 0.f, 0.f, 0.f};
            z = __builtin_amdgcn_mfma_f32_16x16x32_bf16(af0.v, w0, z, 0, 0, 0);
            z = __builtin_amdgcn_mfma_f32_16x16x32_bf16(af1.v, w1, z, 0, 0, 0);
            float bias_d = bias[dt * 16 + cl];
            if (m == 0) {
                #pragma unroll
                for (int r = 0; r < 4; ++r)
                    qb[(size_t)(pix0 + 4 * g + r) * CC + dt * 16 + cl] =
                        (short)bf16bits((z[r] + bias_d) * QSCALE);
            } else if (m == 1) {
                #pragma unroll
                for (int r = 0; r < 4; ++r)
                    kb[(size_t)(pix0 + 4 * g + r) * CC + dt * 16 + cl] =
                        (short)bf16bits(z[r] + bias_d);
            } else {
                #pragma unroll
                for (int r = 0; r < 4; ++r)
                    vtile[(dt * 16 + cl) * 72 + wid * 16 + 4 * g + r] =
                        bf16bits(z[r] + bias_d);
            }
        }
    }
    __syncthreads();
    {
        int d = t >> 2, seg = t & 3;
        uint4 v0 = *(const uint4*)(vtile + d * 72 + seg * 16);
        uint4 v1 = *(const uint4*)(vtile + d * 72 + seg * 16 + 8);
        uint4* dst = (uint4*)(vt + ((size_t)(b * 64 + d)) * NN + pixblk + seg * 16);
        dst[0] = v0; dst[1] = v1;
    }
}

// ---------------- Kernel 3: flash attention, 8 waves x 32q ----------------
// grid = 64 qblocks * KSPLIT = 512; block = 8 waves = 512 thr = 256 q.
// One 32-q tile per wave (small reg footprint -> 4 waves/SIMD target).
// K/V LDS triple-buffered 48KB; depth-2 pipeline with counted vmcnt(2).
__global__ __launch_bounds__(512, 4) void attn_flash(
        const short* __restrict__ qb, const short* __restrict__ kb,
        const short* __restrict__ vt,
        unsigned* __restrict__ obf, float* __restrict__ msb) {
    __shared__ short lds[3][2][64 * 64];   // [buf][K|V][64 rows][64 shorts]
    const int t = threadIdx.x;
    const int lane = t & 63;
    const int wid  = t >> 6;               // 0..7
    const int hi  = lane >> 5;
    const int l31 = lane & 31;
    const int r7  = l31 & 7;
    const int kseg   = blockIdx.x % KSPLIT;
    const int qblock = blockIdx.x / KSPLIT;       // 0..63 (256 q each)
    const int qtile  = qblock * 8 + wid;          // this wave's 32-q tile
    const int b = qblock >> 4;                    // 16 qblocks per batch
    const int key0 = kseg * (NN / KSPLIT);        // within batch

    // Q B-fragments: lane: q=l31, ch=16s+8hi+j
    bf16x8 qf[4];
    const short* qp = qb + (size_t)(qtile * QBLK + l31) * CC + 8 * hi;
    #pragma unroll
    for (int s = 0; s < 4; ++s) qf[s] = *(const bf16x8*)(qp + 16 * s);

    // staging geometry: 512 threads cover 64 rows x 8 col16-units (1 K + 1 V each)
    const int srow = t >> 3;               // 0..63
    const int scol = t & 7;
    const short* kS = kb + ((size_t)b * NN + key0) * CC;   // K rows: 64 shorts
    const short* vS = vt + ((size_t)b * CC) * NN + key0;   // V^T rows: stride NN

    f32x16 oacc0, oacc1;
    #pragma unroll
    for (int r = 0; r < 16; ++r) { oacc0[r] = 0.f; oacc1[r] = 0.f; }
    float psum = 0.f;

    // LDS[buf][0][row][c] = K[row][c ^ (row&7)] (16B units); same for V^T.
    auto stage = [&](int ck, int bsel) {
        const short* srcK = kS + (size_t)(ck * 64 + srow) * CC + (scol ^ (srow & 7)) * 8;
        __builtin_amdgcn_global_load_lds(
            (const __attribute__((address_space(1))) void*)srcK,
            (__attribute__((address_space(3))) void*)&lds[bsel][0][wid * 512],
            16, 0, 0);
        const short* srcV = vS + (size_t)srow * NN + ck * 64 + (scol ^ (srow & 7)) * 8;
        __builtin_amdgcn_global_load_lds(
            (const __attribute__((address_space(1))) void*)srcV,
            (__attribute__((address_space(3))) void*)&lds[bsel][1][wid * 512],
            16, 0, 0);
    };

    auto subbody = [&](const short* kB, const short* vB, int ks) {
        bf16x8 kf[4];
        #pragma unroll
        for (int s = 0; s < 4; ++s)
            kf[s] = *(const bf16x8*)(kB + (32 * ks + l31) * 64 + ((2 * s + hi) ^ r7) * 8);
        bf16x8 vf0 = *(const bf16x8*)(vB + (l31) * 64      + ((4 * ks + 0 + hi) ^ r7) * 8);
        bf16x8 vf1 = *(const bf16x8*)(vB + (32 + l31) * 64 + ((4 * ks + 0 + hi) ^ r7) * 8);
        bf16x8 vf2 = *(const bf16x8*)(vB + (l31) * 64      + ((4 * ks + 2 + hi) ^ r7) * 8);
        bf16x8 vf3 = *(const bf16x8*)(vB + (32 + l31) * 64 + ((4 * ks + 2 + hi) ^ r7) * 8);
        f32x16 st;
        #pragma unroll
        for (int r = 0; r < 16; ++r) st[r] = 0.f;
        #pragma unroll
        for (int s = 0; s < 4; ++s)
            st = __builtin_amdgcn_mfma_f32_32x32x16_bf16(kf[s], qf[s], st, 0, 0, 0);
        float ps = 0.f;
        #pragma unroll
        for (int r = 0; r < 16; ++r) { st[r] = exp2g(st[r]); ps += st[r]; }
        psum += ps;
        unsigned w[8];
        #pragma unroll
        for (int i = 0; i < 8; ++i) w[i] = cvtpk(st[2 * i], st[2 * i + 1]);
        PSWAP(w[0], w[2]); PSWAP(w[1], w[3]);
        PSWAP(w[4], w[6]); PSWAP(w[5], w[7]);
        union { bf16x8 v; unsigned u[4]; } pa0, pa1;
        pa0.u[0] = w[0]; pa0.u[1] = w[1]; pa0.u[2] = w[2]; pa0.u[3] = w[3];
        pa1.u[0] = w[4]; pa1.u[1] = w[5]; pa1.u[2] = w[6]; pa1.u[3] = w[7];
        oacc0 = __builtin_amdgcn_mfma_f32_32x32x16_bf16(pa0.v, vf0, oacc0, 0, 0, 0);
        oacc1 = __builtin_amdgcn_mfma_f32_32x32x16_bf16(pa0.v, vf1, oacc1, 0, 0, 0);
        oacc0 = __builtin_amdgcn_mfma_f32_32x32x16_bf16(pa1.v, vf2, oacc0, 0, 0, 0);
        oacc1 = __builtin_amdgcn_mfma_f32_32x32x16_bf16(pa1.v, vf3, oacc1, 0, 0, 0);
    };

    // depth-2 pipeline: stages c,c+1 in flight; wait only for c (vmcnt(2))
    stage(0, 0);
    stage(1, 1);
    #pragma unroll 1
    for (int c = 0; c < NCHK - 1; ++c) {
        asm volatile("s_waitcnt vmcnt(2)" ::: "memory");   // stage(c) landed
        __builtin_amdgcn_s_barrier();
        if (c + 2 < NCHK) stage(c + 2, (c + 2) % 3);
        const short* kB = &lds[c % 3][0][0];
        const short* vB = &lds[c % 3][1][0];
        subbody(kB, vB, 0);
        subbody(kB, vB, 1);
    }
    asm volatile("s_waitcnt vmcnt(0)" ::: "memory");
    __builtin_amdgcn_s_barrier();
    {
        const int c = NCHK - 1;
        const short* kB = &lds[c % 3][0][0];
        const short* vB = &lds[c % 3][1][0];
        subbody(kB, vB, 0);
        subbody(kB, vB, 1);
    }

    // store partial O packed: word(row,q) = (O[row][l31], O[row][l31+32])
    int task = qtile * KSPLIT + kseg;
    unsigned* ob32 = obf + (size_t)task * 1024;
    #pragma unroll
    for (int r = 0; r < 16; ++r) {
        int row = (r & 3) + 8 * (r >> 2) + 4 * hi;     // query row
        ob32[row * 32 + l31] = cvtpk(oacc0[r], oacc1[r]);
    }
    msb[task * 64 + lane] = psum;
}

// ---------------- Kernel 4: merge partials + out-proj + residual ---------
__device__ __forceinline__ void acc2(float& lo_acc, float& hi_acc, unsigned u) {
    union { unsigned u; float f; } a, b;
    a.u = u << 16; b.u = u & 0xffff0000u;
    lo_acc += a.f; hi_acc += b.f;
}

__global__ __launch_bounds__(256) void attn_merge_outproj(
        const unsigned* __restrict__ obf, const float* __restrict__ msb,
        const short* __restrict__ wfrag,
        const float* __restrict__ x,
        const float* __restrict__ bo,
        float* __restrict__ out) {
    int t = threadIdx.x;
    int lane = t & 63, wid = t >> 6;
    int hi = lane >> 5, l31 = lane & 31;
    int qtile = blockIdx.x * 4 + wid;

    float stot = 0.f;
    #pragma unroll
    for (int s = 0; s < KSPLIT; ++s) {
        stot += msb[(qtile * KSPLIT + s) * 64 + l31]
              + msb[(qtile * KSPLIT + s) * 64 + 32 + l31];
    }
    float inv = 1.f / stot;

    float oa[4][8];
    #pragma unroll
    for (int s = 0; s < 4; ++s)
        #pragma unroll
        for (int j = 0; j < 8; ++j) oa[s][j] = 0.f;
    #pragma unroll 4
    for (int ks = 0; ks < KSPLIT; ++ks) {
        const unsigned* base = obf + (size_t)(qtile * KSPLIT + ks) * 1024 + l31 * 32 + 8 * hi;
        uint4 wa = *(const uint4*)(base);
        uint4 wb = *(const uint4*)(base + 4);
        uint4 wc = *(const uint4*)(base + 16);
        uint4 wd = *(const uint4*)(base + 20);
        acc2(oa[0][0], oa[2][0], wa.x); acc2(oa[0][1], oa[2][1], wa.y);
        acc2(oa[0][2], oa[2][2], wa.z); acc2(oa[0][3], oa[2][3], wa.w);
        acc2(oa[0][4], oa[2][4], wb.x); acc2(oa[0][5], oa[2][5], wb.y);
        acc2(oa[0][6], oa[2][6], wb.z); acc2(oa[0][7], oa[2][7], wb.w);
        acc2(oa[1][0], oa[3][0], wc.x); acc2(oa[1][1], oa[3][1], wc.y);
        acc2(oa[1][2], oa[3][2], wc.z); acc2(oa[1][3], oa[3][3], wc.w);
        acc2(oa[1][4], oa[3][4], wd.x); acc2(oa[1][5], oa[3][5], wd.y);
        acc2(oa[1][6], oa[3][6], wd.z); acc2(oa[1][7], oa[3][7], wd.w);
    }
    union { bf16x8 v; unsigned u[4]; } af[4];
    #pragma unroll
    for (int s = 0; s < 4; ++s)
        #pragma unroll
        for (int m = 0; m < 4; ++m)
            af[s].u[m] = cvtpk(oa[s][2 * m] * inv, oa[s][2 * m + 1] * inv);

    const short* w32 = wfrag + 12288;
    f32x16 z0, z1;
    #pragma unroll
    for (int r = 0; r < 16; ++r) { z0[r] = 0.f; z1[r] = 0.f; }
    #pragma unroll
    for (int s = 0; s < 4; ++s) {
        bf16x8 wb0 = *(const bf16x8*)(w32 + (size_t)((s * 2 + 0) * 64 + lane) * 8);
        bf16x8 wb1 = *(const bf16x8*)(w32 + (size_t)((s * 2 + 1) * 64 + lane) * 8);
        z0 = __builtin_amdgcn_mfma_f32_32x32x16_bf16(af[s].v, wb0, z0, 0, 0, 0);
        z1 = __builtin_amdgcn_mfma_f32_32x32x16_bf16(af[s].v, wb1, z1, 0, 0, 0);
    }
    float bo0 = bo[l31], bo1 = bo[32 + l31];
    #pragma unroll
    for (int r = 0; r < 16; ++r) {
        int row = (r & 3) + 8 * (r >> 2) + 4 * hi;
        size_t i0 = (size_t)(qtile * QBLK + row) * CC + l31;
        out[i0]      = x[i0]      + z0[r] + bo0;
        out[i0 + 32] = x[i0 + 32] + z1[r] + bo1;
    }
}

extern "C" void kernel_launch(void* const* d_in, const int* in_sizes, int n_in,
                              void* d_out, int out_size, void* d_ws, size_t ws_size,
                              hipStream_t stream) {
    const float* x     = (const float*)d_in[0];
    const float* gamma = (const float*)d_in[1];
    const float* beta  = (const float*)d_in[2];
    const float* wq    = (const float*)d_in[3];
    const float* bq    = (const float*)d_in[4];
    const float* wk    = (const float*)d_in[5];
    const float* bk    = (const float*)d_in[6];
    const float* wv    = (const float*)d_in[7];
    const float* bv    = (const float*)d_in[8];
    const float* wo    = (const float*)d_in[9];
    const float* bo    = (const float*)d_in[10];
    float* out = (float*)d_out;

    float* ws    = (float*)d_ws;
    float* part  = ws;                                   // 32768 f32
    short* wfrag = (short*)(part + 32768);               // 16384 bf16
    short* qb    = wfrag + 16384;
    short* kbp   = qb  + (size_t)NPIX * CC;
    short* vtp   = kbp + (size_t)NPIX * CC;
    unsigned* obf = (unsigned*)(vtp + (size_t)NPIX * CC);    // NQT32*KSPLIT*1024 u32
    float* msb   = (float*)(obf + (size_t)NQT32 * KSPLIT * 1024);

    hipLaunchKernelGGL(gn_wt, dim3(272), dim3(256), 0, stream,
                       x, part, wq, wk, wv, wo, wfrag);
    hipLaunchKernelGGL(qkv_proj, dim3(256), dim3(256), 0, stream,
                       x, part, gamma, beta, wfrag, bq, bk, bv, qb, kbp, vtp);
    hipLaunchKernelGGL(attn_flash, dim3(64 * KSPLIT), dim3(512), 0, stream,
                       qb, kbp, vtp, obf, msb);
    hipLaunchKernelGGL(attn_merge_outproj, dim3(NQT32 / 4), dim3(256), 0, stream,
                       obf, msb, wfrag, x, bo, out);
}

// Round 15
// 45.048 us; speedup vs baseline: 2.6435x; 1.0123x over previous
//
#include <hip/hip_runtime.h>
#include <math.h>

#define BB 4
#define HH 64
#define WW 64
#define CC 64
#define NN (HH*WW)          // 4096 pixels per batch
#define NPIX (BB*NN)        // 16384 total pixels
#define EPS 1e-3f
#define QBLK 32
#define KSPLIT 8
#define NQT32 (NPIX/QBLK)   // 512 query tiles of 32
#define NCHK ((NN/KSPLIT)/64)  // 8 chunks of 64 keys per segment

using bf16x8 = __attribute__((ext_vector_type(8))) short;
using f32x4  = __attribute__((ext_vector_type(4))) float;
using f32x16 = __attribute__((ext_vector_type(16))) float;

__device__ inline unsigned short bf16bits(float f) {
    union { float f; unsigned u; } a; a.f = f;
    unsigned r = a.u + 0x7fffu + ((a.u >> 16) & 1u);   // RNE
    return (unsigned short)(r >> 16);
}
__device__ inline unsigned packbf(float lo, float hi) {
    return (unsigned)bf16bits(lo) | ((unsigned)bf16bits(hi) << 16);
}
__device__ inline unsigned cvtpk(float lo, float hi) {
    unsigned r;
    asm("v_cvt_pk_bf16_f32 %0, %1, %2" : "=v"(r) : "v"(lo), "v"(hi));
    return r;
}
#define PSWAP(a, b) asm("v_permlane32_swap_b32 %0, %1" : "+v"(a), "+v"(b))

// raw 2^x (no libm edge handling; inputs are bounded scores)
__device__ __forceinline__ float exp2g(float x) {
    float r;
    asm("v_exp_f32 %0, %1" : "=v"(r) : "v"(x));
    return r;
}

// Q pre-scale: (1/8) * log2(e) so attention softmax uses 2^x directly
#define QSCALE 0.18033688011112042f

// ---------------- Kernel 1: GroupNorm partial sums + weight prep ----------
__global__ __launch_bounds__(256) void gn_wt(const float* __restrict__ x,
                                             float* __restrict__ part,
                                             const float* __restrict__ wq,
                                             const float* __restrict__ wk,
                                             const float* __restrict__ wv,
                                             const float* __restrict__ wo,
                                             short* __restrict__ wfrag) {
    int t = threadIdx.x;
    if (blockIdx.x < 256) {
        int c = t & 63, rr = t >> 6;
        int p0 = blockIdx.x * 64;
        float s = 0.f, s2 = 0.f;
        #pragma unroll
        for (int k = 0; k < 16; ++k) {
            float v = x[(size_t)(p0 + rr + 4 * k) * CC + c];
            s += v; s2 += v * v;
        }
        __shared__ float sA[256], sB[256];
        sA[t] = s; sB[t] = s2;
        __syncthreads();
        if (t < 64) {
            float fs  = sA[t] + sA[64 + t] + sA[128 + t] + sA[192 + t];
            float fs2 = sB[t] + sB[64 + t] + sB[128 + t] + sB[192 + t];
            part[blockIdx.x * 128 + t]      = fs;
            part[blockIdx.x * 128 + 64 + t] = fs2;
        }
    } else {
        const float* mats[3] = {wq, wk, wv};
        int i0 = (blockIdx.x - 256) * 256 + t;
        for (int e = i0; e < 12288; e += 16 * 256) {
            int m = e >> 12;
            int r = e & 4095;
            int dt = r >> 10, h = (r >> 9) & 1, lane = (r >> 3) & 63, j = r & 7;
            int g = lane >> 4, cl = lane & 15;
            float v = mats[m][(h * 32 + g * 8 + j) * 64 + dt * 16 + cl];
            wfrag[e] = (short)bf16bits(v);
        }
        for (int e = i0; e < 4096; e += 16 * 256) {
            int j = e & 7, lane = (e >> 3) & 63, dt = (e >> 9) & 1, s = e >> 10;
            int hi = lane >> 5, l31 = lane & 31;
            float v = wo[(8 * hi + 16 * s + j) * 64 + dt * 32 + l31];
            wfrag[12288 + e] = (short)bf16bits(v);
        }
    }
}

// ---------------- Kernel 2: GN finalize (in-block) + QKV proj via MFMA ----
__global__ __launch_bounds__(256) void qkv_proj(
        const float* __restrict__ x,
        const float* __restrict__ part,
        const float* __restrict__ gamma,
        const float* __restrict__ beta,
        const short* __restrict__ wfrag,
        const float* __restrict__ bq, const float* __restrict__ bk,
        const float* __restrict__ bv,
        short* __restrict__ qb, short* __restrict__ kb,
        short* __restrict__ vt) {
    __shared__ unsigned short vtile[64 * 72];
    __shared__ float sA[256], sB[256];
    __shared__ float sScale[64], sShift[64];
    int t = threadIdx.x;
    int lane = t & 63, wid = t >> 6;
    int g = lane >> 4, cl = lane & 15;
    int pixblk = blockIdx.x * 64;
    int pix0 = pixblk + wid * 16;
    int b = pixblk >> 12;

    // in-block GroupNorm finalize (redundant per block; part is L2-hot)
    {
        int c = t & 63, rr = t >> 6;
        float s = 0.f, s2 = 0.f;
        #pragma unroll
        for (int k = 0; k < 16; ++k) {
            int blk = b * 64 + rr + 4 * k;
            s  += part[blk * 128 + c];
            s2 += part[blk * 128 + 64 + c];
        }
        sA[t] = s; sB[t] = s2;
        __syncthreads();
        if (t < 64) {
            sA[t] = sA[t] + sA[64 + t] + sA[128 + t] + sA[192 + t];
            sB[t] = sB[t] + sB[64 + t] + sB[128 + t] + sB[192 + t];
        }
        __syncthreads();
        if (t < 64) {
            int gg = t >> 1;
            float sumg  = sA[gg * 2] + sA[gg * 2 + 1];
            float sum2g = sB[gg * 2] + sB[gg * 2 + 1];
            const float n = (float)(NN * 2);
            float mean = sumg / n;
            float var  = sum2g / n - mean * mean;
            float r = rsqrtf(var + EPS);
            float a = gamma[t] * r;
            sScale[t] = a;
            sShift[t] = beta[t] - mean * a;
        }
        __syncthreads();
    }

    const float* xp = x + (size_t)(pix0 + cl) * CC + g * 8;
    float4 x00 = *(const float4*)(xp);
    float4 x01 = *(const float4*)(xp + 4);
    float4 x10 = *(const float4*)(xp + 32);
    float4 x11 = *(const float4*)(xp + 36);
    float4 s00 = *(const float4*)(&sScale[g * 8]);
    float4 s01 = *(const float4*)(&sScale[g * 8 + 4]);
    float4 s10 = *(const float4*)(&sScale[g * 8 + 32]);
    float4 s11 = *(const float4*)(&sScale[g * 8 + 36]);
    float4 f00 = *(const float4*)(&sShift[g * 8]);
    float4 f01 = *(const float4*)(&sShift[g * 8 + 4]);
    float4 f10 = *(const float4*)(&sShift[g * 8 + 32]);
    float4 f11 = *(const float4*)(&sShift[g * 8 + 36]);

    union { bf16x8 v; unsigned u[4]; } af0, af1;
    af0.u[0] = packbf(x00.x * s00.x + f00.x, x00.y * s00.y + f00.y);
    af0.u[1] = packbf(x00.z * s00.z + f00.z, x00.w * s00.w + f00.w);
    af0.u[2] = packbf(x01.x * s01.x + f01.x, x01.y * s01.y + f01.y);
    af0.u[3] = packbf(x01.z * s01.z + f01.z, x01.w * s01.w + f01.w);
    af1.u[0] = packbf(x10.x * s10.x + f10.x, x10.y * s10.y + f10.y);
    af1.u[1] = packbf(x10.z * s10.z + f10.z, x10.w * s10.w + f10.w);
    af1.u[2] = packbf(x11.x * s11.x + f11.x, x11.y * s11.y + f11.y);
    af1.u[3] = packbf(x11.z * s11.z + f11.z, x11.w * s11.w + f11.w);

    #pragma unroll
    for (int m = 0; m < 3; ++m) {
        const float* bias = (m == 0) ? bq : (m == 1) ? bk : bv;
        #pragma unroll
        for (int dt = 0; dt < 4; ++dt) {
            bf16x8 w0 = *(const bf16x8*)(wfrag + (size_t)(((m * 4 + dt) * 2 + 0) * 64 + lane) * 8);
            bf16x8 w1 = *(const bf16x8*)(wfrag + (size_t)(((m * 4 + dt) * 2 + 1) * 64 + lane) * 8);
            f32x4 z = (f32x4){0.f, 0.f, 0.f, 0.f};
            z = __builtin_amdgcn_mfma_f32_16x16x32_bf16(af0.v, w0, z, 0, 0, 0);
            z = __builtin_amdgcn_mfma_f32_16x16x32_bf16(af1.v, w1, z, 0, 0, 0);
            float bias_d = bias[dt * 16 + cl];
            if (m == 0) {
                #pragma unroll
                for (int r = 0; r < 4; ++r)
                    qb[(size_t)(pix0 + 4 * g + r) * CC + dt * 16 + cl] =
                        (short)bf16bits((z[r] + bias_d) * QSCALE);
            } else if (m == 1) {
                #pragma unroll
                for (int r = 0; r < 4; ++r)
                    kb[(size_t)(pix0 + 4 * g + r) * CC + dt * 16 + cl] =
                        (short)bf16bits(z[r] + bias_d);
            } else {
                #pragma unroll
                for (int r = 0; r < 4; ++r)
                    vtile[(dt * 16 + cl) * 72 + wid * 16 + 4 * g + r] =
                        bf16bits(z[r] + bias_d);
            }
        }
    }
    __syncthreads();
    {
        int d = t >> 2, seg = t & 3;
        uint4 v0 = *(const uint4*)(vtile + d * 72 + seg * 16);
        uint4 v1 = *(const uint4*)(vtile + d * 72 + seg * 16 + 8);
        uint4* dst = (uint4*)(vt + ((size_t)(b * 64 + d)) * NN + pixblk + seg * 16);
        dst[0] = v0; dst[1] = v1;
    }
}

// ---------------- Kernel 3: flash attention + fused per-kseg out-proj -----
// grid = 64 qblocks * KSPLIT = 512; block = 8 waves = 512 thr = 256 q.
// Epilogue: LDS transpose of O-tile (padded rows, wave-local) -> A-frags ->
// Z = O*Wo via 8 MFMAs -> store Z partials. Merge becomes elementwise.
__global__ __launch_bounds__(512, 4) void attn_flash(
        const short* __restrict__ qb, const short* __restrict__ kb,
        const short* __restrict__ vt, const short* __restrict__ wfrag,
        unsigned* __restrict__ obf, float* __restrict__ msb) {
    __shared__ short lds[3][2][64 * 64];   // [buf][K|V][64 rows][64 shorts]
    const int t = threadIdx.x;
    const int lane = t & 63;
    const int wid  = t >> 6;               // 0..7
    const int hi  = lane >> 5;
    const int l31 = lane & 31;
    const int r7  = l31 & 7;
    const int kseg   = blockIdx.x % KSPLIT;
    const int qblock = blockIdx.x / KSPLIT;       // 0..63 (256 q each)
    const int qtile  = qblock * 8 + wid;          // this wave's 32-q tile
    const int b = qblock >> 4;                    // 16 qblocks per batch
    const int key0 = kseg * (NN / KSPLIT);        // within batch

    // Q B-fragments: lane: q=l31, ch=16s+8hi+j
    bf16x8 qf[4];
    const short* qp = qb + (size_t)(qtile * QBLK + l31) * CC + 8 * hi;
    #pragma unroll
    for (int s = 0; s < 4; ++s) qf[s] = *(const bf16x8*)(qp + 16 * s);

    // staging geometry: 512 threads cover 64 rows x 8 col16-units (1 K + 1 V each)
    const int srow = t >> 3;               // 0..63
    const int scol = t & 7;
    const short* kS = kb + ((size_t)b * NN + key0) * CC;   // K rows: 64 shorts
    const short* vS = vt + ((size_t)b * CC) * NN + key0;   // V^T rows: stride NN

    f32x16 oacc0, oacc1;
    #pragma unroll
    for (int r = 0; r < 16; ++r) { oacc0[r] = 0.f; oacc1[r] = 0.f; }
    float psum = 0.f;

    auto stage = [&](int ck, int bsel) {
        const short* srcK = kS + (size_t)(ck * 64 + srow) * CC + (scol ^ (srow & 7)) * 8;
        __builtin_amdgcn_global_load_lds(
            (const __attribute__((address_space(1))) void*)srcK,
            (__attribute__((address_space(3))) void*)&lds[bsel][0][wid * 512],
            16, 0, 0);
        const short* srcV = vS + (size_t)srow * NN + ck * 64 + (scol ^ (srow & 7)) * 8;
        __builtin_amdgcn_global_load_lds(
            (const __attribute__((address_space(1))) void*)srcV,
            (__attribute__((address_space(3))) void*)&lds[bsel][1][wid * 512],
            16, 0, 0);
    };

    auto subbody = [&](const short* kB, const short* vB, int ks) {
        bf16x8 kf[4];
        #pragma unroll
        for (int s = 0; s < 4; ++s)
            kf[s] = *(const bf16x8*)(kB + (32 * ks + l31) * 64 + ((2 * s + hi) ^ r7) * 8);
        bf16x8 vf0 = *(const bf16x8*)(vB + (l31) * 64      + ((4 * ks + 0 + hi) ^ r7) * 8);
        bf16x8 vf1 = *(const bf16x8*)(vB + (32 + l31) * 64 + ((4 * ks + 0 + hi) ^ r7) * 8);
        bf16x8 vf2 = *(const bf16x8*)(vB + (l31) * 64      + ((4 * ks + 2 + hi) ^ r7) * 8);
        bf16x8 vf3 = *(const bf16x8*)(vB + (32 + l31) * 64 + ((4 * ks + 2 + hi) ^ r7) * 8);
        f32x16 st;
        #pragma unroll
        for (int r = 0; r < 16; ++r) st[r] = 0.f;
        #pragma unroll
        for (int s = 0; s < 4; ++s)
            st = __builtin_amdgcn_mfma_f32_32x32x16_bf16(kf[s], qf[s], st, 0, 0, 0);
        float ps = 0.f;
        #pragma unroll
        for (int r = 0; r < 16; ++r) { st[r] = exp2g(st[r]); ps += st[r]; }
        psum += ps;
        unsigned w[8];
        #pragma unroll
        for (int i = 0; i < 8; ++i) w[i] = cvtpk(st[2 * i], st[2 * i + 1]);
        PSWAP(w[0], w[2]); PSWAP(w[1], w[3]);
        PSWAP(w[4], w[6]); PSWAP(w[5], w[7]);
        union { bf16x8 v; unsigned u[4]; } pa0, pa1;
        pa0.u[0] = w[0]; pa0.u[1] = w[1]; pa0.u[2] = w[2]; pa0.u[3] = w[3];
        pa1.u[0] = w[4]; pa1.u[1] = w[5]; pa1.u[2] = w[6]; pa1.u[3] = w[7];
        oacc0 = __builtin_amdgcn_mfma_f32_32x32x16_bf16(pa0.v, vf0, oacc0, 0, 0, 0);
        oacc1 = __builtin_amdgcn_mfma_f32_32x32x16_bf16(pa0.v, vf1, oacc1, 0, 0, 0);
        oacc0 = __builtin_amdgcn_mfma_f32_32x32x16_bf16(pa1.v, vf2, oacc0, 0, 0, 0);
        oacc1 = __builtin_amdgcn_mfma_f32_32x32x16_bf16(pa1.v, vf3, oacc1, 0, 0, 0);
    };

    // depth-2 pipeline: stages c,c+1 in flight; wait only for c (vmcnt(2))
    stage(0, 0);
    stage(1, 1);
    #pragma unroll 1
    for (int c = 0; c < NCHK - 1; ++c) {
        asm volatile("s_waitcnt vmcnt(2)" ::: "memory");   // stage(c) landed
        __builtin_amdgcn_s_barrier();
        if (c + 2 < NCHK) stage(c + 2, (c + 2) % 3);
        const short* kB = &lds[c % 3][0][0];
        const short* vB = &lds[c % 3][1][0];
        subbody(kB, vB, 0);
        subbody(kB, vB, 1);
    }
    asm volatile("s_waitcnt vmcnt(0)" ::: "memory");
    __builtin_amdgcn_s_barrier();
    {
        const int c = NCHK - 1;
        const short* kB = &lds[c % 3][0][0];
        const short* vB = &lds[c % 3][1][0];
        subbody(kB, vB, 0);
        subbody(kB, vB, 1);
    }

    // ---- epilogue: transpose O tile via LDS, apply Wo, store Z partials ----
    __syncthreads();   // all waves done with K/V buffers; reuse LDS as scratch
    unsigned* scr = (unsigned*)&lds[0][0][0] + (size_t)wid * (32 * 36);
    #pragma unroll
    for (int r = 0; r < 16; ++r) {
        int row = (r & 3) + 8 * (r >> 2) + 4 * hi;     // query row
        scr[row * 36 + l31] = cvtpk(oacc0[r], oacc1[r]);   // (ch l31, ch l31+32)
    }
    // wave-local readback: lane (hi,l31) gathers query l31's channels
    uint4 wa0 = *(const uint4*)(scr + l31 * 36 + 8 * hi);
    uint4 wa1 = *(const uint4*)(scr + l31 * 36 + 8 * hi + 4);
    uint4 wb0_ = *(const uint4*)(scr + l31 * 36 + 16 + 8 * hi);
    uint4 wb1_ = *(const uint4*)(scr + l31 * 36 + 16 + 8 * hi + 4);
    unsigned wA[8] = {wa0.x, wa0.y, wa0.z, wa0.w, wa1.x, wa1.y, wa1.z, wa1.w};
    unsigned wB[8] = {wb0_.x, wb0_.y, wb0_.z, wb0_.w, wb1_.x, wb1_.y, wb1_.z, wb1_.w};
    union { bf16x8 v; unsigned u[4]; } af[4];
    #pragma unroll
    for (int m = 0; m < 4; ++m) {
        af[0].u[m] = (wA[2 * m] & 0xffffu) | (wA[2 * m + 1] << 16);
        af[1].u[m] = (wB[2 * m] & 0xffffu) | (wB[2 * m + 1] << 16);
        af[2].u[m] = (wA[2 * m] >> 16) | (wA[2 * m + 1] & 0xffff0000u);
        af[3].u[m] = (wB[2 * m] >> 16) | (wB[2 * m + 1] & 0xffff0000u);
    }
    const short* w32 = wfrag + 12288;
    f32x16 z0, z1;
    #pragma unroll
    for (int r = 0; r < 16; ++r) { z0[r] = 0.f; z1[r] = 0.f; }
    #pragma unroll
    for (int s = 0; s < 4; ++s) {
        bf16x8 wo0 = *(const bf16x8*)(w32 + (size_t)((s * 2 + 0) * 64 + lane) * 8);
        bf16x8 wo1 = *(const bf16x8*)(w32 + (size_t)((s * 2 + 1) * 64 + lane) * 8);
        z0 = __builtin_amdgcn_mfma_f32_32x32x16_bf16(af[s].v, wo0, z0, 0, 0, 0);
        z1 = __builtin_amdgcn_mfma_f32_32x32x16_bf16(af[s].v, wo1, z1, 0, 0, 0);
    }
    // store Z partials: word(row,l31) = (Z[row][l31], Z[row][l31+32])
    int task = qtile * KSPLIT + kseg;
    unsigned* ob32 = obf + (size_t)task * 1024;
    #pragma unroll
    for (int r = 0; r < 16; ++r) {
        int row = (r & 3) + 8 * (r >> 2) + 4 * hi;
        ob32[row * 32 + l31] = cvtpk(z0[r], z1[r]);
    }
    msb[task * 64 + lane] = psum;
}

// ---------------- Kernel 4: elementwise merge + residual ------------------
// out = x + bo + (Sum_s Z_s) / (Sum_s S_s). 524288 units, grid 2048x256.
__global__ __launch_bounds__(256) void merge_ew(
        const unsigned* __restrict__ obf, const float* __restrict__ msb,
        const float* __restrict__ x, const float* __restrict__ bo,
        float* __restrict__ out) {
    int u = blockIdx.x * 256 + threadIdx.x;      // 0..524287
    int q = u >> 5, c31 = u & 31;
    int qtile = q >> 5;
    int zbase = (qtile * KSPLIT) * 1024 + (q & 31) * 32 + c31;
    int mbase = (qtile * KSPLIT) * 64 + (q & 31);
    float zlo = 0.f, zhi = 0.f, ssum = 0.f;
    #pragma unroll
    for (int s = 0; s < KSPLIT; ++s) {
        unsigned w = obf[zbase + s * 1024];
        union { unsigned u; float f; } a, b2;
        a.u = w << 16; b2.u = w & 0xffff0000u;
        zlo += a.f; zhi += b2.f;
        ssum += msb[mbase + s * 64] + msb[mbase + s * 64 + 32];
    }
    float inv = 1.f / ssum;
    size_t i0 = (size_t)q * CC + c31;
    out[i0]      = x[i0]      + bo[c31]      + zlo * inv;
    out[i0 + 32] = x[i0 + 32] + bo[c31 + 32] + zhi * inv;
}

extern "C" void kernel_launch(void* const* d_in, const int* in_sizes, int n_in,
                              void* d_out, int out_size, void* d_ws, size_t ws_size,
                              hipStream_t stream) {
    const float* x     = (const float*)d_in[0];
    const float* gamma = (const float*)d_in[1];
    const float* beta  = (const float*)d_in[2];
    const float* wq    = (const float*)d_in[3];
    const float* bq    = (const float*)d_in[4];
    const float* wk    = (const float*)d_in[5];
    const float* bk    = (const float*)d_in[6];
    const float* wv    = (const float*)d_in[7];
    const float* bv    = (const float*)d_in[8];
    const float* wo    = (const float*)d_in[9];
    const float* bo    = (const float*)d_in[10];
    float* out = (float*)d_out;

    float* ws    = (float*)d_ws;
    float* part  = ws;                                   // 32768 f32
    short* wfrag = (short*)(part + 32768);               // 16384 bf16
    short* qb    = wfrag + 16384;
    short* kbp   = qb  + (size_t)NPIX * CC;
    short* vtp   = kbp + (size_t)NPIX * CC;
    unsigned* obf = (unsigned*)(vtp + (size_t)NPIX * CC);    // NQT32*KSPLIT*1024 u32
    float* msb   = (float*)(obf + (size_t)NQT32 * KSPLIT * 1024);

    hipLaunchKernelGGL(gn_wt, dim3(272), dim3(256), 0, stream,
                       x, part, wq, wk, wv, wo, wfrag);
    hipLaunchKernelGGL(qkv_proj, dim3(256), dim3(256), 0, stream,
                       x, part, gamma, beta, wfrag, bq, bk, bv, qb, kbp, vtp);
    hipLaunchKernelGGL(attn_flash, dim3(64 * KSPLIT), dim3(512), 0, stream,
                       qb, kbp, vtp, wfrag, obf, msb);
    hipLaunchKernelGGL(merge_ew, dim3(2048), dim3(256), 0, stream,
                       obf, msb, x, bo, out);
}

// Round 16
// 44.896 us; speedup vs baseline: 2.6524x; 1.0034x over previous
//
#include <hip/hip_runtime.h>
#include <math.h>

#define BB 4
#define HH 64
#define WW 64
#define CC 64
#define NN (HH*WW)          // 4096 pixels per batch
#define NPIX (BB*NN)        // 16384 total pixels
#define EPS 1e-3f
#define QBLK 32
#define KSPLIT 4
#define NQT32 (NPIX/QBLK)   // 512 query tiles of 32
#define NCHK ((NN/KSPLIT)/64)  // 16 chunks of 64 keys per segment

using bf16x8 = __attribute__((ext_vector_type(8))) short;
using f32x4  = __attribute__((ext_vector_type(4))) float;
using f32x16 = __attribute__((ext_vector_type(16))) float;

__device__ inline unsigned short bf16bits(float f) {
    union { float f; unsigned u; } a; a.f = f;
    unsigned r = a.u + 0x7fffu + ((a.u >> 16) & 1u);   // RNE
    return (unsigned short)(r >> 16);
}
__device__ inline unsigned packbf(float lo, float hi) {
    return (unsigned)bf16bits(lo) | ((unsigned)bf16bits(hi) << 16);
}
__device__ inline unsigned cvtpk(float lo, float hi) {
    unsigned r;
    asm("v_cvt_pk_bf16_f32 %0, %1, %2" : "=v"(r) : "v"(lo), "v"(hi));
    return r;
}
#define PSWAP(a, b) asm("v_permlane32_swap_b32 %0, %1" : "+v"(a), "+v"(b))

// raw 2^x (no libm edge handling; inputs are bounded scores)
__device__ __forceinline__ float exp2g(float x) {
    float r;
    asm("v_exp_f32 %0, %1" : "=v"(r) : "v"(x));
    return r;
}

// Q pre-scale: (1/8) * log2(e) so attention softmax uses 2^x directly
#define QSCALE 0.18033688011112042f

// ---------------- Kernel 1: GroupNorm partial sums + weight prep ----------
__global__ __launch_bounds__(256) void gn_wt(const float* __restrict__ x,
                                             float* __restrict__ part,
                                             const float* __restrict__ wq,
                                             const float* __restrict__ wk,
                                             const float* __restrict__ wv,
                                             const float* __restrict__ wo,
                                             short* __restrict__ wfrag) {
    int t = threadIdx.x;
    if (blockIdx.x < 256) {
        int c = t & 63, rr = t >> 6;
        int p0 = blockIdx.x * 64;
        float s = 0.f, s2 = 0.f;
        #pragma unroll
        for (int k = 0; k < 16; ++k) {
            float v = x[(size_t)(p0 + rr + 4 * k) * CC + c];
            s += v; s2 += v * v;
        }
        __shared__ float sA[256], sB[256];
        sA[t] = s; sB[t] = s2;
        __syncthreads();
        if (t < 64) {
            float fs  = sA[t] + sA[64 + t] + sA[128 + t] + sA[192 + t];
            float fs2 = sB[t] + sB[64 + t] + sB[128 + t] + sB[192 + t];
            part[blockIdx.x * 128 + t]      = fs;
            part[blockIdx.x * 128 + 64 + t] = fs2;
        }
    } else {
        const float* mats[3] = {wq, wk, wv};
        int i0 = (blockIdx.x - 256) * 256 + t;
        for (int e = i0; e < 12288; e += 16 * 256) {
            int m = e >> 12;
            int r = e & 4095;
            int dt = r >> 10, h = (r >> 9) & 1, lane = (r >> 3) & 63, j = r & 7;
            int g = lane >> 4, cl = lane & 15;
            float v = mats[m][(h * 32 + g * 8 + j) * 64 + dt * 16 + cl];
            wfrag[e] = (short)bf16bits(v);
        }
        for (int e = i0; e < 4096; e += 16 * 256) {
            int j = e & 7, lane = (e >> 3) & 63, dt = (e >> 9) & 1, s = e >> 10;
            int hi = lane >> 5, l31 = lane & 31;
            float v = wo[(8 * hi + 16 * s + j) * 64 + dt * 32 + l31];
            wfrag[12288 + e] = (short)bf16bits(v);
        }
    }
}

// ---------------- Kernel 2: GN finalize (in-block) + QKV proj via MFMA ----
__global__ __launch_bounds__(256) void qkv_proj(
        const float* __restrict__ x,
        const float* __restrict__ part,
        const float* __restrict__ gamma,
        const float* __restrict__ beta,
        const short* __restrict__ wfrag,
        const float* __restrict__ bq, const float* __restrict__ bk,
        const float* __restrict__ bv,
        short* __restrict__ qb, short* __restrict__ kb,
        short* __restrict__ vt) {
    __shared__ unsigned short vtile[64 * 72];
    __shared__ float sA[256], sB[256];
    __shared__ float sScale[64], sShift[64];
    int t = threadIdx.x;
    int lane = t & 63, wid = t >> 6;
    int g = lane >> 4, cl = lane & 15;
    int pixblk = blockIdx.x * 64;
    int pix0 = pixblk + wid * 16;
    int b = pixblk >> 12;

    // in-block GroupNorm finalize (redundant per block; part is L2-hot)
    {
        int c = t & 63, rr = t >> 6;
        float s = 0.f, s2 = 0.f;
        #pragma unroll
        for (int k = 0; k < 16; ++k) {
            int blk = b * 64 + rr + 4 * k;
            s  += part[blk * 128 + c];
            s2 += part[blk * 128 + 64 + c];
        }
        sA[t] = s; sB[t] = s2;
        __syncthreads();
        if (t < 64) {
            sA[t] = sA[t] + sA[64 + t] + sA[128 + t] + sA[192 + t];
            sB[t] = sB[t] + sB[64 + t] + sB[128 + t] + sB[192 + t];
        }
        __syncthreads();
        if (t < 64) {
            int gg = t >> 1;
            float sumg  = sA[gg * 2] + sA[gg * 2 + 1];
            float sum2g = sB[gg * 2] + sB[gg * 2 + 1];
            const float n = (float)(NN * 2);
            float mean = sumg / n;
            float var  = sum2g / n - mean * mean;
            float r = rsqrtf(var + EPS);
            float a = gamma[t] * r;
            sScale[t] = a;
            sShift[t] = beta[t] - mean * a;
        }
        __syncthreads();
    }

    const float* xp = x + (size_t)(pix0 + cl) * CC + g * 8;
    float4 x00 = *(const float4*)(xp);
    float4 x01 = *(const float4*)(xp + 4);
    float4 x10 = *(const float4*)(xp + 32);
    float4 x11 = *(const float4*)(xp + 36);
    float4 s00 = *(const float4*)(&sScale[g * 8]);
    float4 s01 = *(const float4*)(&sScale[g * 8 + 4]);
    float4 s10 = *(const float4*)(&sScale[g * 8 + 32]);
    float4 s11 = *(const float4*)(&sScale[g * 8 + 36]);
    float4 f00 = *(const float4*)(&sShift[g * 8]);
    float4 f01 = *(const float4*)(&sShift[g * 8 + 4]);
    float4 f10 = *(const float4*)(&sShift[g * 8 + 32]);
    float4 f11 = *(const float4*)(&sShift[g * 8 + 36]);

    union { bf16x8 v; unsigned u[4]; } af0, af1;
    af0.u[0] = packbf(x00.x * s00.x + f00.x, x00.y * s00.y + f00.y);
    af0.u[1] = packbf(x00.z * s00.z + f00.z, x00.w * s00.w + f00.w);
    af0.u[2] = packbf(x01.x * s01.x + f01.x, x01.y * s01.y + f01.y);
    af0.u[3] = packbf(x01.z * s01.z + f01.z, x01.w * s01.w + f01.w);
    af1.u[0] = packbf(x10.x * s10.x + f10.x, x10.y * s10.y + f10.y);
    af1.u[1] = packbf(x10.z * s10.z + f10.z, x10.w * s10.w + f10.w);
    af1.u[2] = packbf(x11.x * s11.x + f11.x, x11.y * s11.y + f11.y);
    af1.u[3] = packbf(x11.z * s11.z + f11.z, x11.w * s11.w + f11.w);

    #pragma unroll
    for (int m = 0; m < 3; ++m) {
        const float* bias = (m == 0) ? bq : (m == 1) ? bk : bv;
        #pragma unroll
        for (int dt = 0; dt < 4; ++dt) {
            bf16x8 w0 = *(const bf16x8*)(wfrag + (size_t)(((m * 4 + dt) * 2 + 0) * 64 + lane) * 8);
            bf16x8 w1 = *(const bf16x8*)(wfrag + (size_t)(((m * 4 + dt) * 2 + 1) * 64 + lane) * 8);
            f32x4 z = (f32x4){0.f, 0.f, 0.f, 0.f};
            z = __builtin_amdgcn_mfma_f32_16x16x32_bf16(af0.v, w0, z, 0, 0, 0);
            z = __builtin_amdgcn_mfma_f32_16x16x32_bf16(af1.v, w1, z, 0, 0, 0);
            float bias_d = bias[dt * 16 + cl];
            if (m == 0) {
                #pragma unroll
                for (int r = 0; r < 4; ++r)
                    qb[(size_t)(pix0 + 4 * g + r) * CC + dt * 16 + cl] =
                        (short)bf16bits((z[r] + bias_d) * QSCALE);
            } else if (m == 1) {
                #pragma unroll
                for (int r = 0; r < 4; ++r)
                    kb[(size_t)(pix0 + 4 * g + r) * CC + dt * 16 + cl] =
                        (short)bf16bits(z[r] + bias_d);
            } else {
                #pragma unroll
                for (int r = 0; r < 4; ++r)
                    vtile[(dt * 16 + cl) * 72 + wid * 16 + 4 * g + r] =
                        bf16bits(z[r] + bias_d);
            }
        }
    }
    __syncthreads();
    {
        int d = t >> 2, seg = t & 3;
        uint4 v0 = *(const uint4*)(vtile + d * 72 + seg * 16);
        uint4 v1 = *(const uint4*)(vtile + d * 72 + seg * 16 + 8);
        uint4* dst = (uint4*)(vt + ((size_t)(b * 64 + d)) * NN + pixblk + seg * 16);
        dst[0] = v0; dst[1] = v1;
    }
}

// ---------------- Kernel 3: flash attention + fused per-kseg out-proj -----
// grid = 128 qblocks * KSPLIT(4) = 512; block = 4 waves = 256 thr = 128 q.
// Per wave: 32 q, 1024 keys in 16 chunks of 64. XCD x serves kseg x%4 only.
__global__ __launch_bounds__(256, 2) void attn_flash(
        const short* __restrict__ qb, const short* __restrict__ kb,
        const short* __restrict__ vt, const short* __restrict__ wfrag,
        unsigned* __restrict__ obf, float* __restrict__ msb) {
    __shared__ short lds[3][2][64 * 64];   // [buf][K|V][64 rows][64 shorts]
    const int t = threadIdx.x;
    const int lane = t & 63;
    const int wid  = t >> 6;               // 0..3
    const int hi  = lane >> 5;
    const int l31 = lane & 31;
    const int r7  = l31 & 7;
    const int kseg   = blockIdx.x % KSPLIT;
    const int qblock = blockIdx.x / KSPLIT;       // 0..127 (128 q each)
    const int qtile  = qblock * 4 + wid;          // this wave's 32-q tile
    const int b = qblock >> 5;                    // 32 qblocks per batch
    const int key0 = kseg * (NN / KSPLIT);        // within batch

    // Q B-fragments: lane: q=l31, ch=16s+8hi+j
    bf16x8 qf[4];
    const short* qp = qb + (size_t)(qtile * QBLK + l31) * CC + 8 * hi;
    #pragma unroll
    for (int s = 0; s < 4; ++s) qf[s] = *(const bf16x8*)(qp + 16 * s);

    // staging geometry: 256 threads cover 32 rows x 8 col16-units per round
    const int srow = t >> 3;               // 0..31
    const int scol = t & 7;
    const short* kS = kb + ((size_t)b * NN + key0) * CC;   // K rows: 64 shorts
    const short* vS = vt + ((size_t)b * CC) * NN + key0;   // V^T rows: stride NN

    f32x16 oacc0, oacc1;
    #pragma unroll
    for (int r = 0; r < 16; ++r) { oacc0[r] = 0.f; oacc1[r] = 0.f; }
    float psum = 0.f;

    // 4 global_load_lds per thread per stage (2 K + 2 V), swizzled source
    auto stage = [&](int ck, int bsel) {
        #pragma unroll
        for (int r = 0; r < 2; ++r) {
            int row = srow + 32 * r;
            const short* src = kS + (size_t)(ck * 64 + row) * CC + (scol ^ (row & 7)) * 8;
            __builtin_amdgcn_global_load_lds(
                (const __attribute__((address_space(1))) void*)src,
                (__attribute__((address_space(3))) void*)&lds[bsel][0][(r * 32 + wid * 8) * 64],
                16, 0, 0);
        }
        #pragma unroll
        for (int r = 0; r < 2; ++r) {
            int row = srow + 32 * r;
            const short* src = vS + (size_t)row * NN + ck * 64 + (scol ^ (row & 7)) * 8;
            __builtin_amdgcn_global_load_lds(
                (const __attribute__((address_space(1))) void*)src,
                (__attribute__((address_space(3))) void*)&lds[bsel][1][(r * 32 + wid * 8) * 64],
                16, 0, 0);
        }
    };

    auto subbody = [&](const short* kB, const short* vB, int ks) {
        bf16x8 kf[4];
        #pragma unroll
        for (int s = 0; s < 4; ++s)
            kf[s] = *(const bf16x8*)(kB + (32 * ks + l31) * 64 + ((2 * s + hi) ^ r7) * 8);
        bf16x8 vf0 = *(const bf16x8*)(vB + (l31) * 64      + ((4 * ks + 0 + hi) ^ r7) * 8);
        bf16x8 vf1 = *(const bf16x8*)(vB + (32 + l31) * 64 + ((4 * ks + 0 + hi) ^ r7) * 8);
        bf16x8 vf2 = *(const bf16x8*)(vB + (l31) * 64      + ((4 * ks + 2 + hi) ^ r7) * 8);
        bf16x8 vf3 = *(const bf16x8*)(vB + (32 + l31) * 64 + ((4 * ks + 2 + hi) ^ r7) * 8);
        f32x16 st;
        #pragma unroll
        for (int r = 0; r < 16; ++r) st[r] = 0.f;
        #pragma unroll
        for (int s = 0; s < 4; ++s)
            st = __builtin_amdgcn_mfma_f32_32x32x16_bf16(kf[s], qf[s], st, 0, 0, 0);
        float ps = 0.f;
        #pragma unroll
        for (int r = 0; r < 16; ++r) { st[r] = exp2g(st[r]); ps += st[r]; }
        psum += ps;
        unsigned w[8];
        #pragma unroll
        for (int i = 0; i < 8; ++i) w[i] = cvtpk(st[2 * i], st[2 * i + 1]);
        PSWAP(w[0], w[2]); PSWAP(w[1], w[3]);
        PSWAP(w[4], w[6]); PSWAP(w[5], w[7]);
        union { bf16x8 v; unsigned u[4]; } pa0, pa1;
        pa0.u[0] = w[0]; pa0.u[1] = w[1]; pa0.u[2] = w[2]; pa0.u[3] = w[3];
        pa1.u[0] = w[4]; pa1.u[1] = w[5]; pa1.u[2] = w[6]; pa1.u[3] = w[7];
        oacc0 = __builtin_amdgcn_mfma_f32_32x32x16_bf16(pa0.v, vf0, oacc0, 0, 0, 0);
        oacc1 = __builtin_amdgcn_mfma_f32_32x32x16_bf16(pa0.v, vf1, oacc1, 0, 0, 0);
        oacc0 = __builtin_amdgcn_mfma_f32_32x32x16_bf16(pa1.v, vf2, oacc0, 0, 0, 0);
        oacc1 = __builtin_amdgcn_mfma_f32_32x32x16_bf16(pa1.v, vf3, oacc1, 0, 0, 0);
    };

    // depth-2 pipeline: stages c,c+1 in flight; wait only for c (vmcnt(4))
    stage(0, 0);
    stage(1, 1);
    #pragma unroll 1
    for (int c = 0; c < NCHK - 1; ++c) {
        asm volatile("s_waitcnt vmcnt(4)" ::: "memory");   // stage(c) landed
        __builtin_amdgcn_s_barrier();
        if (c + 2 < NCHK) stage(c + 2, (c + 2) % 3);
        const short* kB = &lds[c % 3][0][0];
        const short* vB = &lds[c % 3][1][0];
        subbody(kB, vB, 0);
        subbody(kB, vB, 1);
    }
    asm volatile("s_waitcnt vmcnt(0)" ::: "memory");
    __builtin_amdgcn_s_barrier();
    {
        const int c = NCHK - 1;
        const short* kB = &lds[c % 3][0][0];
        const short* vB = &lds[c % 3][1][0];
        subbody(kB, vB, 0);
        subbody(kB, vB, 1);
    }

    // ---- epilogue: transpose O tile via LDS, apply Wo, store Z partials ----
    __syncthreads();   // all waves done with K/V buffers; reuse LDS as scratch
    unsigned* scr = (unsigned*)&lds[0][0][0] + (size_t)wid * (32 * 36);
    #pragma unroll
    for (int r = 0; r < 16; ++r) {
        int row = (r & 3) + 8 * (r >> 2) + 4 * hi;     // query row
        scr[row * 36 + l31] = cvtpk(oacc0[r], oacc1[r]);   // (ch l31, ch l31+32)
    }
    // wave-local readback: lane (hi,l31) gathers query l31's channels
    uint4 wa0 = *(const uint4*)(scr + l31 * 36 + 8 * hi);
    uint4 wa1 = *(const uint4*)(scr + l31 * 36 + 8 * hi + 4);
    uint4 wb0_ = *(const uint4*)(scr + l31 * 36 + 16 + 8 * hi);
    uint4 wb1_ = *(const uint4*)(scr + l31 * 36 + 16 + 8 * hi + 4);
    unsigned wA[8] = {wa0.x, wa0.y, wa0.z, wa0.w, wa1.x, wa1.y, wa1.z, wa1.w};
    unsigned wB[8] = {wb0_.x, wb0_.y, wb0_.z, wb0_.w, wb1_.x, wb1_.y, wb1_.z, wb1_.w};
    union { bf16x8 v; unsigned u[4]; } af[4];
    #pragma unroll
    for (int m = 0; m < 4; ++m) {
        af[0].u[m] = (wA[2 * m] & 0xffffu) | (wA[2 * m + 1] << 16);
        af[1].u[m] = (wB[2 * m] & 0xffffu) | (wB[2 * m + 1] << 16);
        af[2].u[m] = (wA[2 * m] >> 16) | (wA[2 * m + 1] & 0xffff0000u);
        af[3].u[m] = (wB[2 * m] >> 16) | (wB[2 * m + 1] & 0xffff0000u);
    }
    const short* w32 = wfrag + 12288;
    f32x16 z0, z1;
    #pragma unroll
    for (int r = 0; r < 16; ++r) { z0[r] = 0.f; z1[r] = 0.f; }
    #pragma unroll
    for (int s = 0; s < 4; ++s) {
        bf16x8 wo0 = *(const bf16x8*)(w32 + (size_t)((s * 2 + 0) * 64 + lane) * 8);
        bf16x8 wo1 = *(const bf16x8*)(w32 + (size_t)((s * 2 + 1) * 64 + lane) * 8);
        z0 = __builtin_amdgcn_mfma_f32_32x32x16_bf16(af[s].v, wo0, z0, 0, 0, 0);
        z1 = __builtin_amdgcn_mfma_f32_32x32x16_bf16(af[s].v, wo1, z1, 0, 0, 0);
    }
    // store Z partials: word(row,l31) = (Z[row][l31], Z[row][l31+32])
    int task = qtile * KSPLIT + kseg;
    unsigned* ob32 = obf + (size_t)task * 1024;
    #pragma unroll
    for (int r = 0; r < 16; ++r) {
        int row = (r & 3) + 8 * (r >> 2) + 4 * hi;
        ob32[row * 32 + l31] = cvtpk(z0[r], z1[r]);
    }
    msb[task * 64 + lane] = psum;
}

// ---------------- Kernel 4: elementwise merge + residual ------------------
// out = x + bo + (Sum_s Z_s) / (Sum_s S_s). 524288 units, grid 2048x256.
__global__ __launch_bounds__(256) void merge_ew(
        const unsigned* __restrict__ obf, const float* __restrict__ msb,
        const float* __restrict__ x, const float* __restrict__ bo,
        float* __restrict__ out) {
    int u = blockIdx.x * 256 + threadIdx.x;      // 0..524287
    int q = u >> 5, c31 = u & 31;
    int qtile = q >> 5;
    int zbase = (qtile * KSPLIT) * 1024 + (q & 31) * 32 + c31;
    int mbase = (qtile * KSPLIT) * 64 + (q & 31);
    float zlo = 0.f, zhi = 0.f, ssum = 0.f;
    #pragma unroll
    for (int s = 0; s < KSPLIT; ++s) {
        unsigned w = obf[zbase + s * 1024];
        union { unsigned u; float f; } a, b2;
        a.u = w << 16; b2.u = w & 0xffff0000u;
        zlo += a.f; zhi += b2.f;
        ssum += msb[mbase + s * 64] + msb[mbase + s * 64 + 32];
    }
    float inv = 1.f / ssum;
    size_t i0 = (size_t)q * CC + c31;
    out[i0]      = x[i0]      + bo[c31]      + zlo * inv;
    out[i0 + 32] = x[i0 + 32] + bo[c31 + 32] + zhi * inv;
}

extern "C" void kernel_launch(void* const* d_in, const int* in_sizes, int n_in,
                              void* d_out, int out_size, void* d_ws, size_t ws_size,
                              hipStream_t stream) {
    const float* x     = (const float*)d_in[0];
    const float* gamma = (const float*)d_in[1];
    const float* beta  = (const float*)d_in[2];
    const float* wq    = (const float*)d_in[3];
    const float* bq    = (const float*)d_in[4];
    const float* wk    = (const float*)d_in[5];
    const float* bk    = (const float*)d_in[6];
    const float* wv    = (const float*)d_in[7];
    const float* bv    = (const float*)d_in[8];
    const float* wo    = (const float*)d_in[9];
    const float* bo    = (const float*)d_in[10];
    float* out = (float*)d_out;

    float* ws    = (float*)d_ws;
    float* part  = ws;                                   // 32768 f32
    short* wfrag = (short*)(part + 32768);               // 16384 bf16
    short* qb    = wfrag + 16384;
    short* kbp   = qb  + (size_t)NPIX * CC;
    short* vtp   = kbp + (size_t)NPIX * CC;
    unsigned* obf = (unsigned*)(vtp + (size_t)NPIX * CC);    // NQT32*KSPLIT*1024 u32
    float* msb   = (float*)(obf + (size_t)NQT32 * KSPLIT * 1024);

    hipLaunchKernelGGL(gn_wt, dim3(272), dim3(256), 0, stream,
                       x, part, wq, wk, wv, wo, wfrag);
    hipLaunchKernelGGL(qkv_proj, dim3(256), dim3(256), 0, stream,
                       x, part, gamma, beta, wfrag, bq, bk, bv, qb, kbp, vtp);
    hipLaunchKernelGGL(attn_flash, dim3(128 * KSPLIT), dim3(256), 0, stream,
                       qb, kbp, vtp, wfrag, obf, msb);
    hipLaunchKernelGGL(merge_ew, dim3(2048), dim3(256), 0, stream,
                       obf, msb, x, bo, out);
}